// Round 8
// baseline (383.450 us; speedup 1.0000x reference)
//
#include <hip/hip_runtime.h>
#include <hip/hip_bf16.h>
#include <math.h>

// Problem constants
#define Bv   4
#define LQv  1024
#define Cv   256
#define Hv   8
#define Lv   4
#define Pv   4
#define DFFv 1024
#define DHv  32
#define LSRCv 21760   // 128*128 + 64*64 + 32*32 + 16*16

typedef __attribute__((ext_vector_type(8))) short bhalf8;   // 8 bf16 (4 VGPRs)
typedef __attribute__((ext_vector_type(4))) float floatx4;  // MFMA acc

// fp32 -> bf16 RNE, packed pair
__device__ inline unsigned pk_bf16x2(float x, float y) {
    unsigned xb = __float_as_uint(x), yb = __float_as_uint(y);
    unsigned xr = (xb + 0x7FFFu + ((xb >> 16) & 1u)) >> 16;
    unsigned yr = (yb + 0x7FFFu + ((yb >> 16) & 1u)) >> 16;
    return xr | (yr << 16);
}
__device__ inline unsigned short bf16_1(float x) {
    unsigned xb = __float_as_uint(x);
    return (unsigned short)((xb + 0x7FFFu + ((xb >> 16) & 1u)) >> 16);
}
__device__ inline float ubf2f(unsigned short u) {
    return __uint_as_float(((unsigned)u) << 16);
}

// ---------------------------------------------------------------------------
// Weight pre-conversion: f32 [N][K] -> bf16 in FRAGMENT-SHUFFLED layout so that
// in-GEMM B-fragment loads are 64-lane contiguous 1KB streams:
//   ushort index = ((n>>4)*(K>>5) + (k>>5))*512 + ((k>>3)&3)*128 + (n&15)*8 + (k&7)
// Segments (f32 offsets): in_w 0, sa_w 196608, val_w 262144,
// MERGED off_w+aw_w 327680 (N=384: off rows n=0..255, aw rows n=256..383),
// co_w 425984, f1_w 491520, f2_w 753664; total 1015808 f32.
// Block gridDim-1 additionally builds the concatenated off/aw bias (384 f32).
__global__ __launch_bounds__(256) void cvt_weights(const float* __restrict__ in_w,
                                                   const float* __restrict__ sa_w,
                                                   const float* __restrict__ val_w,
                                                   const float* __restrict__ off_w,
                                                   const float* __restrict__ aw_w,
                                                   const float* __restrict__ co_w,
                                                   const float* __restrict__ f1_w,
                                                   const float* __restrict__ f2_w,
                                                   const float* __restrict__ off_b,
                                                   const float* __restrict__ aw_b,
                                                   unsigned short* __restrict__ wp,
                                                   float* __restrict__ cbias) {
    const size_t idx4 = (size_t)blockIdx.x * 256 + threadIdx.x;   // float4 index
    if (idx4 >= 253952) {                                          // 1015808/4
        const int t = (int)(idx4 - 253952);
        if (t < 256) cbias[t] = off_b[t];
        else if (t < 384) cbias[t] = aw_b[t - 256];
        return;
    }
    const size_t f = idx4 * 4;
    const float* src; size_t off; int K; size_t obase; int nadd = 0;
    if (f < 196608)      { src = in_w;  off = f;          K = 256;  obase = 0; }
    else if (f < 262144) { src = sa_w;  off = f - 196608; K = 256;  obase = 196608; }
    else if (f < 327680) { src = val_w; off = f - 262144; K = 256;  obase = 262144; }
    else if (f < 393216) { src = off_w; off = f - 327680; K = 256;  obase = 327680; }
    else if (f < 425984) { src = aw_w;  off = f - 393216; K = 256;  obase = 327680; nadd = 256; }
    else if (f < 491520) { src = co_w;  off = f - 425984; K = 256;  obase = 425984; }
    else if (f < 753664) { src = f1_w;  off = f - 491520; K = 256;  obase = 491520; }
    else                 { src = f2_w;  off = f - 753664; K = 1024; obase = 753664; }
    float4 v = *(const float4*)(src + off);
    const int n = (int)(off / (size_t)K) + nadd, k = (int)(off % (size_t)K);
    const size_t di = obase + ((size_t)((n >> 4) * (K >> 5) + (k >> 5))) * 512
                    + (size_t)(((k >> 3) & 3) * 128 + (n & 15) * 8 + (k & 7));
    *(uint2*)(wp + di) = (uint2){pk_bf16x2(v.x, v.y), pk_bf16x2(v.z, v.w)};
}

// ---------------------------------------------------------------------------
// bf16-MFMA GEMM v9b: C[M,N] = (A[+A2])[M,K] @ W[N,K]^T + bias[N].
//  - PERSISTENT MULTI-PANEL blocks: each block owns one 64-col panel and NP
//    consecutive 64-row panels -> NP*K/128 chunks streamed through one
//    double-buffered LDS pipeline. Prologue HBM latency and W loads amortized
//    NP x; C-stores of panel p overlap A-loads of panel p+1.
//  - K=256 path: ALL W fragments hoisted to registers once per block
//    (16 x bhalf8 = 64 VGPR). v9b: panel loop with TWO EXPLICIT PHASES so
//    every wfr[][] index is compile-time (rule #20: runtime-indexed
//    ext_vector arrays demote to scratch). Steady-state loop has ZERO global
//    loads other than the A stream.
//  - __launch_bounds__(256,3): 170-VGPR budget fits the ~140-VGPR hoisted
//    path with no spill (v6 lesson). LDS 2x[64][136] = 34.8 KB.
//  - XCD-BIJECTIVE swizzle (v6, FETCH 174->71 MB proven). Requires
//    ((M/64)/NP) % 8 == 0.
//  - K=1024 fallback (f2): v8 per-chunk W loads, NP must be 1.
__global__ __launch_bounds__(256, 3) void gemm_mfma(const float* __restrict__ A,
                                                    const float* __restrict__ A2,
                                                    const unsigned short* __restrict__ Wp,
                                                    const float* __restrict__ bias,
                                                    float* __restrict__ Cf,
                                                    unsigned short* __restrict__ Ch,
                                                    int M, int N, int K, int relu,
                                                    int NP) {
    __shared__ __attribute__((aligned(16))) unsigned short As[2][64 * 136]; // 34816 B
    const unsigned bid = blockIdx.x;
    const unsigned nc = (unsigned)N >> 6;
    const unsigned xcd = bid & 7, j = bid >> 3;
    const unsigned cpan = j % nc, gk = j / nc;
    const int grp = (int)(xcd + 8 * gk);
    const int bm0 = grp * NP * 64;
    const int bn = (int)(cpan << 6);
    const int tid = threadIdx.x;
    const int wid = tid >> 6, lane = tid & 63;
    const int wr = wid >> 1, wc = wid & 1;       // wave tile: rows wr*32, cols wc*32
    const int col16 = lane & 15;
    const int quad = lane >> 4;

    // staging: thread covers rows (tid>>4) + 16j (j=0..3), f32 cols
    // (tid&15)*4 + 64i (i=0..1) of a 64x128 chunk -> 8 float4 loads.
    const int srow0 = tid >> 4;            // 0..15
    const int scol = (tid & 15) * 4;       // 0..60
    const float* asrc = A + (size_t)(bm0 + srow0) * K + scol;
    const float* a2src = A2 ? A2 + (size_t)(bm0 + srow0) * K + scol : nullptr;

    const int K32 = K >> 5;
    const unsigned short* wbase = Wp + ((size_t)((bn >> 4) + wc * 2) * K32) * 512
                                + (size_t)lane * 8;

    // bias hoist (2 scalar loads per thread)
    float bv[2];
    bv[0] = bias[bn + wc * 32 + col16];
    bv[1] = bias[bn + wc * 32 + 16 + col16];

    floatx4 acc[2][2] = {};
    float4 rv[4][2];

    auto loadA = [&](int p, int c) {
        const float* base = asrc + (size_t)(p * 64) * K + c * 128;
#pragma unroll
        for (int j2 = 0; j2 < 4; ++j2)
#pragma unroll
            for (int i = 0; i < 2; ++i)
                rv[j2][i] = *(const float4*)(base + (size_t)(16 * j2) * K + 64 * i);
        if (a2src) {
            const float* base2 = a2src + (size_t)(p * 64) * K + c * 128;
#pragma unroll
            for (int j2 = 0; j2 < 4; ++j2)
#pragma unroll
                for (int i = 0; i < 2; ++i) {
                    float4 t = *(const float4*)(base2 + (size_t)(16 * j2) * K + 64 * i);
                    rv[j2][i].x += t.x; rv[j2][i].y += t.y;
                    rv[j2][i].z += t.z; rv[j2][i].w += t.w;
                }
        }
    };
    auto writeA = [&](int buf) {
#pragma unroll
        for (int j2 = 0; j2 < 4; ++j2)
#pragma unroll
            for (int i = 0; i < 2; ++i) {
                uint2 p = {pk_bf16x2(rv[j2][i].x, rv[j2][i].y),
                           pk_bf16x2(rv[j2][i].z, rv[j2][i].w)};
                *(uint2*)&As[buf][(srow0 + 16 * j2) * 136 + scol + 64 * i] = p;
            }
    };

    if (K32 == 8) {
        // ---- K=256: W fully register-resident (16 frags = 64 VGPR)
        bhalf8 wfr[2][8];
#pragma unroll
        for (int nt = 0; nt < 2; ++nt)
#pragma unroll
            for (int k2 = 0; k2 < 8; ++k2)
                wfr[nt][k2] = *(const bhalf8*)(wbase + (size_t)(nt * 8 + k2) * 512);

        loadA(0, 0);
        writeA(0);

        for (int p = 0; p < NP; ++p) {
            // ---- phase 0: compute As[0] (k 0..127), prefetch (p,1)
            __syncthreads();
            loadA(p, 1);
            {
                const unsigned short* ab = As[0];
#pragma unroll
                for (int s = 0; s < 4; ++s) {
                    bhalf8 af[2];
#pragma unroll
                    for (int mt = 0; mt < 2; ++mt)
                        af[mt] = *(const bhalf8*)&ab[(wr * 32 + mt * 16 + col16) * 136 + s * 32 + quad * 8];
#pragma unroll
                    for (int mt = 0; mt < 2; ++mt)
#pragma unroll
                        for (int nt = 0; nt < 2; ++nt)
                            acc[mt][nt] = __builtin_amdgcn_mfma_f32_16x16x32_bf16(
                                af[mt], wfr[nt][s], acc[mt][nt], 0, 0, 0);
                }
            }
            writeA(1);

            // ---- phase 1: compute As[1] (k 128..255), prefetch (p+1,0)
            __syncthreads();
            if (p + 1 < NP) loadA(p + 1, 0);
            {
                const unsigned short* ab = As[1];
#pragma unroll
                for (int s = 0; s < 4; ++s) {
                    bhalf8 af[2];
#pragma unroll
                    for (int mt = 0; mt < 2; ++mt)
                        af[mt] = *(const bhalf8*)&ab[(wr * 32 + mt * 16 + col16) * 136 + s * 32 + quad * 8];
#pragma unroll
                    for (int mt = 0; mt < 2; ++mt)
#pragma unroll
                        for (int nt = 0; nt < 2; ++nt)
                            acc[mt][nt] = __builtin_amdgcn_mfma_f32_16x16x32_bf16(
                                af[mt], wfr[nt][4 + s], acc[mt][nt], 0, 0, 0);
                }
            }

            // ---- panel p done: store C (overlaps next panel's A-loads), reset acc
            {
                const int rowb = bm0 + p * 64 + wr * 32;
#pragma unroll
                for (int mt = 0; mt < 2; ++mt)
#pragma unroll
                    for (int nt = 0; nt < 2; ++nt)
#pragma unroll
                        for (int i = 0; i < 4; ++i) {
                            const int col = bn + wc * 32 + nt * 16 + col16;
                            const int row = rowb + mt * 16 + quad * 4 + i;
                            float v = acc[mt][nt][i] + bv[nt];
                            if (relu) v = fmaxf(v, 0.f);
                            if (Ch) Ch[(size_t)row * N + col] = bf16_1(v);
                            else    Cf[(size_t)row * N + col] = v;
                            acc[mt][nt][i] = 0.f;
                        }
            }
            if (p + 1 < NP) writeA(0);
        }
    } else {
        // ---- K=1024 fallback (f2): per-chunk W loads, NP == 1.
        // (Runtime c only forms LDS/global ADDRESSES here, never register
        //  array indices -> no scratch demotion.)
        const int NC = K >> 7;
        loadA(0, 0);
        writeA(0);
        for (int c = 0; c < NC; ++c) {
            __syncthreads();
            if (c + 1 < NC) loadA(0, c + 1);
            const unsigned short* ab = As[c & 1];
#pragma unroll
            for (int s = 0; s < 4; ++s) {
                bhalf8 bfr[2];
#pragma unroll
                for (int nt = 0; nt < 2; ++nt)
                    bfr[nt] = *(const bhalf8*)(wbase + ((size_t)(nt * K32 + c * 4 + s)) * 512);
                bhalf8 af[2];
#pragma unroll
                for (int mt = 0; mt < 2; ++mt)
                    af[mt] = *(const bhalf8*)&ab[(wr * 32 + mt * 16 + col16) * 136 + s * 32 + quad * 8];
#pragma unroll
                for (int mt = 0; mt < 2; ++mt)
#pragma unroll
                    for (int nt = 0; nt < 2; ++nt)
                        acc[mt][nt] = __builtin_amdgcn_mfma_f32_16x16x32_bf16(
                            af[mt], bfr[nt], acc[mt][nt], 0, 0, 0);
            }
            if (c + 1 < NC) writeA((c + 1) & 1);
        }
#pragma unroll
        for (int mt = 0; mt < 2; ++mt)
#pragma unroll
            for (int nt = 0; nt < 2; ++nt)
#pragma unroll
                for (int i = 0; i < 4; ++i) {
                    const int col = bn + wc * 32 + nt * 16 + col16;
                    const int row = bm0 + wr * 32 + mt * 16 + quad * 4 + i;
                    float v = acc[mt][nt][i] + bv[nt];
                    if (relu) v = fmaxf(v, 0.f);
                    if (Ch) Ch[(size_t)row * N + col] = bf16_1(v);
                    else    Cf[(size_t)row * N + col] = v;
                }
    }
}

// ---------------------------------------------------------------------------
// MFMA flash self-attention. grid (LQ/64, H, B), block 256 = 4 waves.
// Q/K read with configurable row stride (they live in one [M,512] buffer).
#define ATT_SCALE 0.17677669529663687f
__global__ __launch_bounds__(256, 2) void attn_mfma(const float* __restrict__ Q,
                                                    const float* __restrict__ Kb,
                                                    const float* __restrict__ Vb,
                                                    float* __restrict__ O,
                                                    int qk_stride) {
    const int b = blockIdx.z, h = blockIdx.y, qt = blockIdx.x;
    const int tid = threadIdx.x;
    const int wid = tid >> 6, lane = tid & 63;
    const int col16 = lane & 15, quad = lane >> 4;

    __shared__ unsigned short smem_us[40960];
    unsigned short* Ks = smem_us + wid * 9600;
    unsigned short* Vt = Ks + 2560;
    unsigned short* Ps = Ks + 4864;
    float* corr_s = (float*)(Ks + 9472);
    unsigned short* Qs = smem_us + 38400;

    // ---- stage Q (scaled) once, whole block
    {
        const int row = tid >> 2, part = tid & 3;
        const float* qsrc = Q + ((size_t)(b * LQv + qt * 64 + row)) * qk_stride + h * DHv + part * 8;
        float4 qa = *(const float4*)qsrc;
        float4 qb2 = *(const float4*)(qsrc + 4);
        uint4 qp = {pk_bf16x2(qa.x * ATT_SCALE, qa.y * ATT_SCALE),
                    pk_bf16x2(qa.z * ATT_SCALE, qa.w * ATT_SCALE),
                    pk_bf16x2(qb2.x * ATT_SCALE, qb2.y * ATT_SCALE),
                    pk_bf16x2(qb2.z * ATT_SCALE, qb2.w * ATT_SCALE)};
        *(uint4*)&Qs[row * 40 + part * 8] = qp;
    }
    __syncthreads();
    bhalf8 qfr[4];
#pragma unroll
    for (int j = 0; j < 4; ++j)
        qfr[j] = *(const bhalf8*)&Qs[(j * 16 + col16) * 40 + quad * 8];

    float m_state[4] = {-1e30f, -1e30f, -1e30f, -1e30f};
    float l_state[4] = {0.f, 0.f, 0.f, 0.f};
    floatx4 acc_o[4][2] = {};
    const int dd = lane & 31, half = lane >> 5;

    const float* kbase = Kb + ((size_t)(b * LQv + wid * 256)) * qk_stride + h * DHv;
    const float* vbase = Vb + ((size_t)(b * LQv + wid * 256)) * Cv + h * DHv;

#pragma unroll 1
    for (int t = 0; t < 4; ++t) {
        {
            const float* ks = kbase + (size_t)(t * 64 + lane) * qk_stride;
            float4 f0 = *(const float4*)(ks + 0),  f1 = *(const float4*)(ks + 4);
            float4 f2 = *(const float4*)(ks + 8),  f3 = *(const float4*)(ks + 12);
            float4 f4 = *(const float4*)(ks + 16), f5 = *(const float4*)(ks + 20);
            float4 f6 = *(const float4*)(ks + 24), f7 = *(const float4*)(ks + 28);
            uint4 p0 = {pk_bf16x2(f0.x, f0.y), pk_bf16x2(f0.z, f0.w),
                        pk_bf16x2(f1.x, f1.y), pk_bf16x2(f1.z, f1.w)};
            uint4 p1 = {pk_bf16x2(f2.x, f2.y), pk_bf16x2(f2.z, f2.w),
                        pk_bf16x2(f3.x, f3.y), pk_bf16x2(f3.z, f3.w)};
            uint4 p2 = {pk_bf16x2(f4.x, f4.y), pk_bf16x2(f4.z, f4.w),
                        pk_bf16x2(f5.x, f5.y), pk_bf16x2(f5.z, f5.w)};
            uint4 p3 = {pk_bf16x2(f6.x, f6.y), pk_bf16x2(f6.z, f6.w),
                        pk_bf16x2(f7.x, f7.y), pk_bf16x2(f7.z, f7.w)};
            *(uint4*)&Ks[lane * 40 + 0]  = p0;
            *(uint4*)&Ks[lane * 40 + 8]  = p1;
            *(uint4*)&Ks[lane * 40 + 16] = p2;
            *(uint4*)&Ks[lane * 40 + 24] = p3;
        }
        {
            const float* vs = vbase + (size_t)(t * 64 + half * 32) * Cv + dd;
#pragma unroll
            for (int j4 = 0; j4 < 8; ++j4) {
                float g0 = vs[(j4 * 4 + 0) * Cv], g1 = vs[(j4 * 4 + 1) * Cv];
                float g2 = vs[(j4 * 4 + 2) * Cv], g3 = vs[(j4 * 4 + 3) * Cv];
                uint2 vp = {pk_bf16x2(g0, g1), pk_bf16x2(g2, g3)};
                *(uint2*)&Vt[dd * 72 + half * 32 + j4 * 4] = vp;
            }
        }

        floatx4 accs[4][4] = {};
        bhalf8 af[4];
#pragma unroll
        for (int kf = 0; kf < 4; ++kf)
            af[kf] = *(const bhalf8*)&Ks[(kf * 16 + col16) * 40 + quad * 8];
#pragma unroll
        for (int kf = 0; kf < 4; ++kf)
#pragma unroll
            for (int qf = 0; qf < 4; ++qf)
                accs[kf][qf] = __builtin_amdgcn_mfma_f32_16x16x32_bf16(
                    af[kf], qfr[qf], accs[kf][qf], 0, 0, 0);

#pragma unroll
        for (int qf = 0; qf < 4; ++qf) {
            float tmax = -1e30f;
#pragma unroll
            for (int kf = 0; kf < 4; ++kf) {
                tmax = fmaxf(tmax, fmaxf(fmaxf(accs[kf][qf][0], accs[kf][qf][1]),
                                         fmaxf(accs[kf][qf][2], accs[kf][qf][3])));
            }
            tmax = fmaxf(tmax, __shfl_xor(tmax, 16));
            tmax = fmaxf(tmax, __shfl_xor(tmax, 32));
            float mnew = fmaxf(m_state[qf], tmax);
            float cr = __expf(m_state[qf] - mnew);
            m_state[qf] = mnew;
            float psum = 0.f;
#pragma unroll
            for (int kf = 0; kf < 4; ++kf) {
                float p0 = __expf(accs[kf][qf][0] - mnew);
                float p1 = __expf(accs[kf][qf][1] - mnew);
                float p2 = __expf(accs[kf][qf][2] - mnew);
                float p3 = __expf(accs[kf][qf][3] - mnew);
                psum += (p0 + p1) + (p2 + p3);
                uint2 pp = {pk_bf16x2(p0, p1), pk_bf16x2(p2, p3)};
                *(uint2*)&Ps[(qf * 16 + col16) * 72 + kf * 16 + quad * 4] = pp;
            }
            psum += __shfl_xor(psum, 16);
            psum += __shfl_xor(psum, 32);
            l_state[qf] = l_state[qf] * cr + psum;
            if (quad == 0) corr_s[qf * 16 + col16] = cr;
        }

#pragma unroll
        for (int mf = 0; mf < 4; ++mf) {
            float4 cv = *(const float4*)&corr_s[mf * 16 + quad * 4];
#pragma unroll
            for (int nf = 0; nf < 2; ++nf) {
                acc_o[mf][nf][0] *= cv.x;
                acc_o[mf][nf][1] *= cv.y;
                acc_o[mf][nf][2] *= cv.z;
                acc_o[mf][nf][3] *= cv.w;
            }
        }
#pragma unroll
        for (int ks2 = 0; ks2 < 2; ++ks2) {
            bhalf8 pf[4], vf[2];
#pragma unroll
            for (int mf = 0; mf < 4; ++mf)
                pf[mf] = *(const bhalf8*)&Ps[(mf * 16 + col16) * 72 + ks2 * 32 + quad * 8];
#pragma unroll
            for (int nf = 0; nf < 2; ++nf)
                vf[nf] = *(const bhalf8*)&Vt[(nf * 16 + col16) * 72 + ks2 * 32 + quad * 8];
#pragma unroll
            for (int mf = 0; mf < 4; ++mf)
#pragma unroll
                for (int nf = 0; nf < 2; ++nf)
                    acc_o[mf][nf] = __builtin_amdgcn_mfma_f32_16x16x32_bf16(
                        pf[mf], vf[nf], acc_o[mf][nf], 0, 0, 0);
        }
    }

    __syncthreads();
    float* mbuf = (float*)smem_us;
    float* lbuf = mbuf + 256;
    float* obuf = lbuf + 256;
    if (quad == 0) {
#pragma unroll
        for (int qf = 0; qf < 4; ++qf) {
            mbuf[wid * 64 + qf * 16 + col16] = m_state[qf];
            lbuf[wid * 64 + qf * 16 + col16] = l_state[qf];
        }
    }
#pragma unroll
    for (int mf = 0; mf < 4; ++mf)
#pragma unroll
        for (int nf = 0; nf < 2; ++nf)
#pragma unroll
            for (int i = 0; i < 4; ++i)
                obuf[wid * 2048 + (mf * 16 + quad * 4 + i) * 32 + nf * 16 + col16] =
                    acc_o[mf][nf][i];
    __syncthreads();
    {
        const int q = tid >> 2, dg = (tid & 3) * 8;
        float m0 = mbuf[q], m1 = mbuf[64 + q], m2 = mbuf[128 + q], m3 = mbuf[192 + q];
        float gm = fmaxf(fmaxf(m0, m1), fmaxf(m2, m3));
        float e0 = __expf(m0 - gm), e1 = __expf(m1 - gm);
        float e2 = __expf(m2 - gm), e3 = __expf(m3 - gm);
        float lt = lbuf[q] * e0 + lbuf[64 + q] * e1 + lbuf[128 + q] * e2 + lbuf[192 + q] * e3;
        float inv = 1.f / lt;
        const float* o0 = obuf + q * 32 + dg;
        float* orow = O + ((size_t)(b * LQv + qt * 64 + q)) * Cv + h * DHv + dg;
        float ov[8];
#pragma unroll
        for (int d = 0; d < 8; ++d)
            ov[d] = (o0[d] * e0 + o0[2048 + d] * e1 + o0[4096 + d] * e2 + o0[6144 + d] * e3) * inv;
        *(float4*)(orow) = make_float4(ov[0], ov[1], ov[2], ov[3]);
        *(float4*)(orow + 4) = make_float4(ov[4], ov[5], ov[6], ov[7]);
    }
}

// ---------------------------------------------------------------------------
// Deformable sampling over bf16 value. grid: B*LQ blocks, 256 thr = (h, d).
// offs+aw come MERGED in one [B*LQ][384] buffer: cols 0-255 offsets, 256-383 aw.
__global__ __launch_bounds__(256) void deform_sample(const unsigned short* __restrict__ value,
                                                     const float* __restrict__ oab,
                                                     const float* __restrict__ ref,
                                                     float* __restrict__ out) {
    const int bq = blockIdx.x;          // b*LQ + q
    const int b = bq >> 10;
    const int tid = threadIdx.x;
    const int h = tid >> 5, d = tid & 31;

    const float* aw = oab + (size_t)bq * 384 + 256 + h * 16;
    float w[16];
    float mx = -1e30f;
#pragma unroll
    for (int j = 0; j < 16; ++j) { w[j] = aw[j]; mx = fmaxf(mx, w[j]); }
    float ssum = 0.f;
#pragma unroll
    for (int j = 0; j < 16; ++j) { w[j] = __expf(w[j] - mx); ssum += w[j]; }
    float invs = 1.f / ssum;

    const float* op = oab + (size_t)bq * 384 + h * 32;
    const float* rp = ref + (size_t)bq * (Lv * 2);

    const int starts[4] = {0, 16384, 20480, 21504};
    const int WHl[4] = {128, 64, 32, 16};

    float acc = 0.f;
#pragma unroll 1
    for (int l = 0; l < 4; ++l) {
        const int wl = WHl[l];
        const float rx = rp[l * 2 + 0], ry = rp[l * 2 + 1];
        const unsigned short* vb0 = value + ((size_t)b * LSRCv + starts[l]) * Cv + h * DHv + d;
#pragma unroll 1
        for (int p = 0; p < 4; ++p) {
            float ox = op[l * 8 + p * 2 + 0], oy = op[l * 8 + p * 2 + 1];
            float x = rx * (float)wl + ox - 0.5f;
            float y = ry * (float)wl + oy - 0.5f;
            float fx0 = floorf(x), fy0 = floorf(y);
            int x0 = (int)fx0, y0 = (int)fy0;
            float tx = x - fx0, ty = y - fy0;
            float w00 = (1.f - tx) * (1.f - ty);
            float w10 = tx * (1.f - ty);
            float w01 = (1.f - tx) * ty;
            float w11 = tx * ty;
            float s = 0.f;
            bool xin0 = (x0 >= 0) & (x0 < wl);
            bool xin1 = (x0 + 1 >= 0) & (x0 + 1 < wl);
            bool yin0 = (y0 >= 0) & (y0 < wl);
            bool yin1 = (y0 + 1 >= 0) & (y0 + 1 < wl);
            if (yin0) {
                if (xin0) s = fmaf(w00, ubf2f(vb0[(size_t)(y0 * wl + x0) * Cv]), s);
                if (xin1) s = fmaf(w10, ubf2f(vb0[(size_t)(y0 * wl + x0 + 1) * Cv]), s);
            }
            if (yin1) {
                if (xin0) s = fmaf(w01, ubf2f(vb0[(size_t)((y0 + 1) * wl + x0) * Cv]), s);
                if (xin1) s = fmaf(w11, ubf2f(vb0[(size_t)((y0 + 1) * wl + x0 + 1) * Cv]), s);
            }
            acc = fmaf(w[l * 4 + p] * invs, s, acc);
        }
    }
    out[(size_t)bq * Cv + h * DHv + d] = acc;
}

// ---------------------------------------------------------------------------
// out = LayerNorm(x + r) * g + b    one block per row of 256
__global__ __launch_bounds__(256) void ln_residual(const float* __restrict__ x,
                                                   const float* __restrict__ r,
                                                   const float* __restrict__ g,
                                                   const float* __restrict__ bta,
                                                   float* __restrict__ out) {
    const int row = blockIdx.x;
    const int tid = threadIdx.x;
    float v = x[(size_t)row * Cv + tid] + r[(size_t)row * Cv + tid];
    float s = v, sq = v * v;
#pragma unroll
    for (int off = 32; off > 0; off >>= 1) {
        s  += __shfl_down(s, off, 64);
        sq += __shfl_down(sq, off, 64);
    }
    __shared__ float ss[4], sqq[4];
    int wid = tid >> 6;
    if ((tid & 63) == 0) { ss[wid] = s; sqq[wid] = sq; }
    __syncthreads();
    __shared__ float meansh, rstdsh;
    if (tid == 0) {
        float S = ss[0] + ss[1] + ss[2] + ss[3];
        float Q = sqq[0] + sqq[1] + sqq[2] + sqq[3];
        float mean = S * (1.f / Cv);
        float var = Q * (1.f / Cv) - mean * mean;
        meansh = mean;
        rstdsh = rsqrtf(var + 1e-5f);
    }
    __syncthreads();
    out[(size_t)row * Cv + tid] = (v - meansh) * rstdsh * g[tid] + bta[tid];
}

// ---------------------------------------------------------------------------
extern "C" void kernel_launch(void* const* d_in, const int* in_sizes, int n_in,
                              void* d_out, int out_size, void* d_ws, size_t ws_size,
                              hipStream_t stream) {
    const float* tgt       = (const float*)d_in[0];
    const float* query_pos = (const float*)d_in[1];
    const float* ref_pts   = (const float*)d_in[2];
    const float* src       = (const float*)d_in[3];
    const float* in_w      = (const float*)d_in[4];
    const float* in_b      = (const float*)d_in[5];
    const float* sa_w      = (const float*)d_in[6];
    const float* sa_b      = (const float*)d_in[7];
    const float* off_w     = (const float*)d_in[8];
    const float* off_b     = (const float*)d_in[9];
    const float* aw_w      = (const float*)d_in[10];
    const float* aw_b      = (const float*)d_in[11];
    const float* val_w     = (const float*)d_in[12];
    const float* val_b     = (const float*)d_in[13];
    const float* co_w      = (const float*)d_in[14];
    const float* co_b      = (const float*)d_in[15];
    const float* ln1_g     = (const float*)d_in[16];
    const float* ln1_b     = (const float*)d_in[17];
    const float* ln2_g     = (const float*)d_in[18];
    const float* ln2_b     = (const float*)d_in[19];
    const float* ln3_g     = (const float*)d_in[20];
    const float* ln3_b     = (const float*)d_in[21];
    const float* f1_w      = (const float*)d_in[22];
    const float* f1_b      = (const float*)d_in[23];
    const float* f2_w      = (const float*)d_in[24];
    const float* f2_b      = (const float*)d_in[25];

    const int M0  = Bv * LQv * Cv;          // 1048576
    const int VSZ = Bv * LSRCv * Cv;        // 22282240
    float* ws = (float*)d_ws;

    // Phase-A buffers alias the (later) bf16 value region — lifetimes disjoint.
    float* big    = ws;                     // VSZ floats
    float* qkbuf  = big;                    // [4096][512]: q cols 0-255, k 256-511
    float* vb     = big + (size_t)2 * M0;
    float* ob     = big + (size_t)3 * M0;
    unsigned short* value16 = (unsigned short*)big;   // VSZ ushorts (phase B)
    // bf16 weights + concat bias in the tail of the big region.
    unsigned short* wb = (unsigned short*)(big + (size_t)20000000);
    float* cbias  = big + (size_t)20510000;           // 384 f32
    float* tgt_a  = ws + (size_t)VSZ;
    float* oabuf  = tgt_a + M0;             // [4096][384] merged offsets+aw
    float* sampled= oabuf + (size_t)Bv * LQv * 384;
    float* tgt_b  = sampled + M0;
    float* hidden = tgt_b + M0;             // B*LQ*DFF
    float* tmp    = hidden + (size_t)Bv * LQv * DFFv;

    // Fragment-shuffled bf16 weight segment offsets (ushort units)
    const size_t WB_IN = 0, WB_SA = 196608, WB_VAL = 262144, WB_OA = 327680,
                 WB_CO = 425984, WB_F1 = 491520, WB_F2 = 753664;

    const int Mq = Bv * LQv;                // 4096 rows
    dim3 blk256(256);

    // 0. pre-convert all weights to fragment-shuffled bf16 (one-time, ~2MB)
    cvt_weights<<<dim3(993), blk256, 0, stream>>>(
        in_w, sa_w, val_w, off_w, aw_w, co_w, f1_w, f2_w, off_b, aw_b, wb, cbias);

    // 1. fused q+k projection: A = tgt + query_pos, W = in_w rows 0-511
    gemm_mfma<<<dim3((Mq / 64) * (512 / 64)), blk256, 0, stream>>>(
        tgt, query_pos, wb + WB_IN, in_b, qkbuf, nullptr, Mq, 512, Cv, 0, 1);
    // 2. v projection (in_w rows 512-767)
    gemm_mfma<<<dim3((Mq / 64) * (Cv / 64)), blk256, 0, stream>>>(
        tgt, nullptr, wb + WB_IN + 131072, in_b + 2 * Cv, vb, nullptr, Mq, Cv, Cv, 0, 1);

    // 3. self-attention (MFMA flash; Q/K strided in qkbuf)
    attn_mfma<<<dim3(LQv / 64, Hv, Bv), blk256, 0, stream>>>(qkbuf, qkbuf + 256, vb, ob, 512);

    // 4. output projection, 5. LN2 residual
    gemm_mfma<<<dim3((Mq / 64) * (Cv / 64)), blk256, 0, stream>>>(
        ob, nullptr, wb + WB_SA, sa_b, tmp, nullptr, Mq, Cv, Cv, 0, 1);
    ln_residual<<<dim3(Mq), blk256, 0, stream>>>(tgt, tmp, ln2_g, ln2_b, tgt_a);

    // 6. value projection (big GEMM) -> bf16. 1360 panels, NP=5 -> 272 groups
    //    (272 % 8 == 0, swizzle bijective), grid 272*4 = 1088 blocks.
    gemm_mfma<<<dim3((((Bv * LSRCv) / 64) / 5) * (Cv / 64)), blk256, 0, stream>>>(
        src, nullptr, wb + WB_VAL, val_b, nullptr, value16, Bv * LSRCv, Cv, Cv, 0, 5);

    // 7. MERGED offsets + aw logits GEMM (N=384, fused add A = tgt_a + query_pos)
    gemm_mfma<<<dim3((Mq / 64) * (384 / 64)), blk256, 0, stream>>>(
        tgt_a, query_pos, wb + WB_OA, cbias, oabuf, nullptr, Mq, 384, Cv, 0, 1);

    // 8. deformable bilinear sampling (bf16 value)
    deform_sample<<<dim3(Bv * LQv), blk256, 0, stream>>>(value16, oabuf, ref_pts, sampled);

    // 9. cross-attn output projection, LN1 residual
    gemm_mfma<<<dim3((Mq / 64) * (Cv / 64)), blk256, 0, stream>>>(
        sampled, nullptr, wb + WB_CO, co_b, tmp, nullptr, Mq, Cv, Cv, 0, 1);
    ln_residual<<<dim3(Mq), blk256, 0, stream>>>(tgt_a, tmp, ln1_g, ln1_b, tgt_b);

    // 10. FFN + LN3 -> d_out
    gemm_mfma<<<dim3((Mq / 64) * (DFFv / 64)), blk256, 0, stream>>>(
        tgt_b, nullptr, wb + WB_F1, f1_b, hidden, nullptr, Mq, DFFv, Cv, 1, 1);
    gemm_mfma<<<dim3((Mq / 64) * (Cv / 64)), blk256, 0, stream>>>(
        hidden, nullptr, wb + WB_F2, f2_b, tmp, nullptr, Mq, Cv, DFFv, 0, 1);
    ln_residual<<<dim3(Mq), blk256, 0, stream>>>(tgt_b, tmp, ln3_g, ln3_b, (float*)d_out);
}

// Round 9
// 362.588 us; speedup vs baseline: 1.0575x; 1.0575x over previous
//
#include <hip/hip_runtime.h>
#include <hip/hip_bf16.h>
#include <math.h>

// Problem constants
#define Bv   4
#define LQv  1024
#define Cv   256
#define Hv   8
#define Lv   4
#define Pv   4
#define DFFv 1024
#define DHv  32
#define LSRCv 21760   // 128*128 + 64*64 + 32*32 + 16*16

typedef __attribute__((ext_vector_type(8))) short bhalf8;   // 8 bf16 (4 VGPRs)
typedef __attribute__((ext_vector_type(4))) float floatx4;  // MFMA acc

// fp32 -> bf16 RNE, packed pair
__device__ inline unsigned pk_bf16x2(float x, float y) {
    unsigned xb = __float_as_uint(x), yb = __float_as_uint(y);
    unsigned xr = (xb + 0x7FFFu + ((xb >> 16) & 1u)) >> 16;
    unsigned yr = (yb + 0x7FFFu + ((yb >> 16) & 1u)) >> 16;
    return xr | (yr << 16);
}
__device__ inline unsigned short bf16_1(float x) {
    unsigned xb = __float_as_uint(x);
    return (unsigned short)((xb + 0x7FFFu + ((xb >> 16) & 1u)) >> 16);
}
__device__ inline float ubf2f(unsigned short u) {
    return __uint_as_float(((unsigned)u) << 16);
}

// ---------------------------------------------------------------------------
// Weight pre-conversion: f32 [N][K] -> bf16 in FRAGMENT-SHUFFLED layout so that
// in-GEMM B-fragment loads are 64-lane contiguous 1KB streams:
//   ushort index = ((n>>4)*(K>>5) + (k>>5))*512 + ((k>>3)&3)*128 + (n&15)*8 + (k&7)
// Segments (f32 offsets): in_w 0, sa_w 196608, val_w 262144,
// MERGED off_w+aw_w 327680 (N=384: off rows n=0..255, aw rows n=256..383),
// co_w 425984, f1_w 491520, f2_w 753664; total 1015808 f32.
// Block gridDim-1 additionally builds the concatenated off/aw bias (384 f32).
__global__ __launch_bounds__(256) void cvt_weights(const float* __restrict__ in_w,
                                                   const float* __restrict__ sa_w,
                                                   const float* __restrict__ val_w,
                                                   const float* __restrict__ off_w,
                                                   const float* __restrict__ aw_w,
                                                   const float* __restrict__ co_w,
                                                   const float* __restrict__ f1_w,
                                                   const float* __restrict__ f2_w,
                                                   const float* __restrict__ off_b,
                                                   const float* __restrict__ aw_b,
                                                   unsigned short* __restrict__ wp,
                                                   float* __restrict__ cbias) {
    const size_t idx4 = (size_t)blockIdx.x * 256 + threadIdx.x;   // float4 index
    if (idx4 >= 253952) {                                          // 1015808/4
        const int t = (int)(idx4 - 253952);
        if (t < 256) cbias[t] = off_b[t];
        else if (t < 384) cbias[t] = aw_b[t - 256];
        return;
    }
    const size_t f = idx4 * 4;
    const float* src; size_t off; int K; size_t obase; int nadd = 0;
    if (f < 196608)      { src = in_w;  off = f;          K = 256;  obase = 0; }
    else if (f < 262144) { src = sa_w;  off = f - 196608; K = 256;  obase = 196608; }
    else if (f < 327680) { src = val_w; off = f - 262144; K = 256;  obase = 262144; }
    else if (f < 393216) { src = off_w; off = f - 327680; K = 256;  obase = 327680; }
    else if (f < 425984) { src = aw_w;  off = f - 393216; K = 256;  obase = 327680; nadd = 256; }
    else if (f < 491520) { src = co_w;  off = f - 425984; K = 256;  obase = 425984; }
    else if (f < 753664) { src = f1_w;  off = f - 491520; K = 256;  obase = 491520; }
    else                 { src = f2_w;  off = f - 753664; K = 1024; obase = 753664; }
    float4 v = *(const float4*)(src + off);
    const int n = (int)(off / (size_t)K) + nadd, k = (int)(off % (size_t)K);
    const size_t di = obase + ((size_t)((n >> 4) * (K >> 5) + (k >> 5))) * 512
                    + (size_t)(((k >> 3) & 3) * 128 + (n & 15) * 8 + (k & 7));
    *(uint2*)(wp + di) = (uint2){pk_bf16x2(v.x, v.y), pk_bf16x2(v.z, v.w)};
}

// ---------------------------------------------------------------------------
// v10: v8's proven GEMM body (best measured: value GEMM 60.5 us) as a device
// function so independent GEMMs can be FUSED INTO ONE DISPATCH (block-range
// partition). 64x64 tile, BK=128, 4 waves, double-buffered LDS, drain-proof
// schedule, XCD-bijective swizzle, pre-shuffled bf16 W.
// Requirements: (M/64)%8==0, N%64==0, K%128==0.
struct GJob {
    const float* A; const float* A2;
    const unsigned short* Wp; const float* bias;
    float* Cf; unsigned short* Ch;
    int M, N, K, relu;
};

__device__ __forceinline__ void gemm_body(unsigned short* AsBase,   // 2 x 64*136
                                          const float* __restrict__ A,
                                          const float* __restrict__ A2,
                                          const unsigned short* __restrict__ Wp,
                                          const float* __restrict__ bias,
                                          float* __restrict__ Cf,
                                          unsigned short* __restrict__ Ch,
                                          int N, int K, int relu, unsigned bid) {
    const unsigned nc = (unsigned)N >> 6;
    const unsigned xcd = bid & 7, j = bid >> 3;
    const unsigned cpan = j % nc, r8 = j / nc;
    const int bm = (int)((xcd + (r8 << 3)) << 6);
    const int bn = (int)(cpan << 6);
    const int tid = threadIdx.x;
    const int wid = tid >> 6, lane = tid & 63;
    const int wr = wid >> 1, wc = wid & 1;       // wave tile: rows wr*32, cols wc*32
    const int col16 = lane & 15;
    const int quad = lane >> 4;

    // staging: thread covers rows (tid>>4) + 16j (j=0..3), f32 cols
    // (tid&15)*4 + 64i (i=0..1) of the 64x128 chunk -> 8 float4 loads.
    const int srow0 = tid >> 4;            // 0..15
    const int scol = (tid & 15) * 4;       // 0..60
    const float* asrc = A + (size_t)(bm + srow0) * K + scol;
    const float* a2src = A2 ? A2 + (size_t)(bm + srow0) * K + scol : nullptr;

    const int K32 = K >> 5;
    const unsigned short* wbase = Wp + ((size_t)((bn >> 4) + wc * 2) * K32) * 512
                                + (size_t)lane * 8;

    floatx4 acc[2][2] = {};
    float4 rv[4][2];

    auto loadA = [&](int c) {
#pragma unroll
        for (int j2 = 0; j2 < 4; ++j2)
#pragma unroll
            for (int i = 0; i < 2; ++i)
                rv[j2][i] = *(const float4*)(asrc + (size_t)(16 * j2) * K + c * 128 + 64 * i);
        if (a2src) {
#pragma unroll
            for (int j2 = 0; j2 < 4; ++j2)
#pragma unroll
                for (int i = 0; i < 2; ++i) {
                    float4 t = *(const float4*)(a2src + (size_t)(16 * j2) * K + c * 128 + 64 * i);
                    rv[j2][i].x += t.x; rv[j2][i].y += t.y;
                    rv[j2][i].z += t.z; rv[j2][i].w += t.w;
                }
        }
    };
    auto writeA = [&](int buf) {
        unsigned short* dst = AsBase + buf * (64 * 136);
#pragma unroll
        for (int j2 = 0; j2 < 4; ++j2)
#pragma unroll
            for (int i = 0; i < 2; ++i) {
                uint2 p = {pk_bf16x2(rv[j2][i].x, rv[j2][i].y),
                           pk_bf16x2(rv[j2][i].z, rv[j2][i].w)};
                *(uint2*)&dst[(srow0 + 16 * j2) * 136 + scol + 64 * i] = p;
            }
    };

    const int NC = K >> 7;                 // chunks of 128
    loadA(0);
    writeA(0);

    for (int c = 0; c < NC; ++c) {
        __syncthreads();                    // buf[c&1] visible block-wide
        if (c + 1 < NC) loadA(c + 1);       // flies over the whole compute phase

        const unsigned short* ab = AsBase + (c & 1) * (64 * 136);
#pragma unroll
        for (int s = 0; s < 4; ++s) {
            bhalf8 bfr[2];
#pragma unroll
            for (int nt = 0; nt < 2; ++nt)
                bfr[nt] = *(const bhalf8*)(wbase + ((size_t)(nt * K32 + c * 4 + s)) * 512);
            bhalf8 af[2];
#pragma unroll
            for (int mt = 0; mt < 2; ++mt)
                af[mt] = *(const bhalf8*)&ab[(wr * 32 + mt * 16 + col16) * 136 + s * 32 + quad * 8];
#pragma unroll
            for (int mt = 0; mt < 2; ++mt)
#pragma unroll
                for (int nt = 0; nt < 2; ++nt)
                    acc[mt][nt] = __builtin_amdgcn_mfma_f32_16x16x32_bf16(
                        af[mt], bfr[nt], acc[mt][nt], 0, 0, 0);
        }

        if (c + 1 < NC) writeA((c + 1) & 1);  // per-wave vmcnt wait only, no barrier
    }

#pragma unroll
    for (int mt = 0; mt < 2; ++mt) {
#pragma unroll
        for (int nt = 0; nt < 2; ++nt) {
            const int col = bn + wc * 32 + nt * 16 + col16;
            const float bv = bias[col];
#pragma unroll
            for (int i = 0; i < 4; ++i) {
                const int row = bm + wr * 32 + mt * 16 + quad * 4 + i;
                float v = acc[mt][nt][i] + bv;
                if (relu) v = fmaxf(v, 0.f);
                if (Ch) Ch[(size_t)row * N + col] = bf16_1(v);
                else    Cf[(size_t)row * N + col] = v;
            }
        }
    }
}

__global__ __launch_bounds__(256, 4) void gemm_single(const float* __restrict__ A,
                                                      const float* __restrict__ A2,
                                                      const unsigned short* __restrict__ Wp,
                                                      const float* __restrict__ bias,
                                                      float* __restrict__ Cf,
                                                      unsigned short* __restrict__ Ch,
                                                      int N, int K, int relu) {
    __shared__ __attribute__((aligned(16))) unsigned short As[2 * 64 * 136]; // 34816 B
    gemm_body(As, A, A2, Wp, bias, Cf, Ch, N, K, relu, blockIdx.x);
}

// Three independent GEMMs in ONE dispatch: blocks [0,c0) run j0, [c0,c01) j1,
// [c01,grid) j2. Fills latency gaps of small GEMMs with big-GEMM blocks.
__global__ __launch_bounds__(256, 4) void gemm_triple(GJob j0, GJob j1, GJob j2,
                                                      unsigned c0, unsigned c01) {
    __shared__ __attribute__((aligned(16))) unsigned short As[2 * 64 * 136]; // 34816 B
    const unsigned b = blockIdx.x;
    if (b < c0) {
        gemm_body(As, j0.A, j0.A2, j0.Wp, j0.bias, j0.Cf, j0.Ch, j0.N, j0.K, j0.relu, b);
    } else if (b < c01) {
        gemm_body(As, j1.A, j1.A2, j1.Wp, j1.bias, j1.Cf, j1.Ch, j1.N, j1.K, j1.relu, b - c0);
    } else {
        gemm_body(As, j2.A, j2.A2, j2.Wp, j2.bias, j2.Cf, j2.Ch, j2.N, j2.K, j2.relu, b - c01);
    }
}

// ---------------------------------------------------------------------------
// MFMA flash self-attention. grid (LQ/64, H, B), block 256 = 4 waves.
// Q/K read with configurable row stride (they live in one [M,512] buffer).
#define ATT_SCALE 0.17677669529663687f
__global__ __launch_bounds__(256, 2) void attn_mfma(const float* __restrict__ Q,
                                                    const float* __restrict__ Kb,
                                                    const float* __restrict__ Vb,
                                                    float* __restrict__ O,
                                                    int qk_stride) {
    const int b = blockIdx.z, h = blockIdx.y, qt = blockIdx.x;
    const int tid = threadIdx.x;
    const int wid = tid >> 6, lane = tid & 63;
    const int col16 = lane & 15, quad = lane >> 4;

    __shared__ unsigned short smem_us[40960];
    unsigned short* Ks = smem_us + wid * 9600;
    unsigned short* Vt = Ks + 2560;
    unsigned short* Ps = Ks + 4864;
    float* corr_s = (float*)(Ks + 9472);
    unsigned short* Qs = smem_us + 38400;

    // ---- stage Q (scaled) once, whole block
    {
        const int row = tid >> 2, part = tid & 3;
        const float* qsrc = Q + ((size_t)(b * LQv + qt * 64 + row)) * qk_stride + h * DHv + part * 8;
        float4 qa = *(const float4*)qsrc;
        float4 qb2 = *(const float4*)(qsrc + 4);
        uint4 qp = {pk_bf16x2(qa.x * ATT_SCALE, qa.y * ATT_SCALE),
                    pk_bf16x2(qa.z * ATT_SCALE, qa.w * ATT_SCALE),
                    pk_bf16x2(qb2.x * ATT_SCALE, qb2.y * ATT_SCALE),
                    pk_bf16x2(qb2.z * ATT_SCALE, qb2.w * ATT_SCALE)};
        *(uint4*)&Qs[row * 40 + part * 8] = qp;
    }
    __syncthreads();
    bhalf8 qfr[4];
#pragma unroll
    for (int j = 0; j < 4; ++j)
        qfr[j] = *(const bhalf8*)&Qs[(j * 16 + col16) * 40 + quad * 8];

    float m_state[4] = {-1e30f, -1e30f, -1e30f, -1e30f};
    float l_state[4] = {0.f, 0.f, 0.f, 0.f};
    floatx4 acc_o[4][2] = {};
    const int dd = lane & 31, half = lane >> 5;

    const float* kbase = Kb + ((size_t)(b * LQv + wid * 256)) * qk_stride + h * DHv;
    const float* vbase = Vb + ((size_t)(b * LQv + wid * 256)) * Cv + h * DHv;

#pragma unroll 1
    for (int t = 0; t < 4; ++t) {
        {
            const float* ks = kbase + (size_t)(t * 64 + lane) * qk_stride;
            float4 f0 = *(const float4*)(ks + 0),  f1 = *(const float4*)(ks + 4);
            float4 f2 = *(const float4*)(ks + 8),  f3 = *(const float4*)(ks + 12);
            float4 f4 = *(const float4*)(ks + 16), f5 = *(const float4*)(ks + 20);
            float4 f6 = *(const float4*)(ks + 24), f7 = *(const float4*)(ks + 28);
            uint4 p0 = {pk_bf16x2(f0.x, f0.y), pk_bf16x2(f0.z, f0.w),
                        pk_bf16x2(f1.x, f1.y), pk_bf16x2(f1.z, f1.w)};
            uint4 p1 = {pk_bf16x2(f2.x, f2.y), pk_bf16x2(f2.z, f2.w),
                        pk_bf16x2(f3.x, f3.y), pk_bf16x2(f3.z, f3.w)};
            uint4 p2 = {pk_bf16x2(f4.x, f4.y), pk_bf16x2(f4.z, f4.w),
                        pk_bf16x2(f5.x, f5.y), pk_bf16x2(f5.z, f5.w)};
            uint4 p3 = {pk_bf16x2(f6.x, f6.y), pk_bf16x2(f6.z, f6.w),
                        pk_bf16x2(f7.x, f7.y), pk_bf16x2(f7.z, f7.w)};
            *(uint4*)&Ks[lane * 40 + 0]  = p0;
            *(uint4*)&Ks[lane * 40 + 8]  = p1;
            *(uint4*)&Ks[lane * 40 + 16] = p2;
            *(uint4*)&Ks[lane * 40 + 24] = p3;
        }
        {
            const float* vs = vbase + (size_t)(t * 64 + half * 32) * Cv + dd;
#pragma unroll
            for (int j4 = 0; j4 < 8; ++j4) {
                float g0 = vs[(j4 * 4 + 0) * Cv], g1 = vs[(j4 * 4 + 1) * Cv];
                float g2 = vs[(j4 * 4 + 2) * Cv], g3 = vs[(j4 * 4 + 3) * Cv];
                uint2 vp = {pk_bf16x2(g0, g1), pk_bf16x2(g2, g3)};
                *(uint2*)&Vt[dd * 72 + half * 32 + j4 * 4] = vp;
            }
        }

        floatx4 accs[4][4] = {};
        bhalf8 af[4];
#pragma unroll
        for (int kf = 0; kf < 4; ++kf)
            af[kf] = *(const bhalf8*)&Ks[(kf * 16 + col16) * 40 + quad * 8];
#pragma unroll
        for (int kf = 0; kf < 4; ++kf)
#pragma unroll
            for (int qf = 0; qf < 4; ++qf)
                accs[kf][qf] = __builtin_amdgcn_mfma_f32_16x16x32_bf16(
                    af[kf], qfr[qf], accs[kf][qf], 0, 0, 0);

#pragma unroll
        for (int qf = 0; qf < 4; ++qf) {
            float tmax = -1e30f;
#pragma unroll
            for (int kf = 0; kf < 4; ++kf) {
                tmax = fmaxf(tmax, fmaxf(fmaxf(accs[kf][qf][0], accs[kf][qf][1]),
                                         fmaxf(accs[kf][qf][2], accs[kf][qf][3])));
            }
            tmax = fmaxf(tmax, __shfl_xor(tmax, 16));
            tmax = fmaxf(tmax, __shfl_xor(tmax, 32));
            float mnew = fmaxf(m_state[qf], tmax);
            float cr = __expf(m_state[qf] - mnew);
            m_state[qf] = mnew;
            float psum = 0.f;
#pragma unroll
            for (int kf = 0; kf < 4; ++kf) {
                float p0 = __expf(accs[kf][qf][0] - mnew);
                float p1 = __expf(accs[kf][qf][1] - mnew);
                float p2 = __expf(accs[kf][qf][2] - mnew);
                float p3 = __expf(accs[kf][qf][3] - mnew);
                psum += (p0 + p1) + (p2 + p3);
                uint2 pp = {pk_bf16x2(p0, p1), pk_bf16x2(p2, p3)};
                *(uint2*)&Ps[(qf * 16 + col16) * 72 + kf * 16 + quad * 4] = pp;
            }
            psum += __shfl_xor(psum, 16);
            psum += __shfl_xor(psum, 32);
            l_state[qf] = l_state[qf] * cr + psum;
            if (quad == 0) corr_s[qf * 16 + col16] = cr;
        }

#pragma unroll
        for (int mf = 0; mf < 4; ++mf) {
            float4 cv = *(const float4*)&corr_s[mf * 16 + quad * 4];
#pragma unroll
            for (int nf = 0; nf < 2; ++nf) {
                acc_o[mf][nf][0] *= cv.x;
                acc_o[mf][nf][1] *= cv.y;
                acc_o[mf][nf][2] *= cv.z;
                acc_o[mf][nf][3] *= cv.w;
            }
        }
#pragma unroll
        for (int ks2 = 0; ks2 < 2; ++ks2) {
            bhalf8 pf[4], vf[2];
#pragma unroll
            for (int mf = 0; mf < 4; ++mf)
                pf[mf] = *(const bhalf8*)&Ps[(mf * 16 + col16) * 72 + ks2 * 32 + quad * 8];
#pragma unroll
            for (int nf = 0; nf < 2; ++nf)
                vf[nf] = *(const bhalf8*)&Vt[(nf * 16 + col16) * 72 + ks2 * 32 + quad * 8];
#pragma unroll
            for (int mf = 0; mf < 4; ++mf)
#pragma unroll
                for (int nf = 0; nf < 2; ++nf)
                    acc_o[mf][nf] = __builtin_amdgcn_mfma_f32_16x16x32_bf16(
                        pf[mf], vf[nf], acc_o[mf][nf], 0, 0, 0);
        }
    }

    __syncthreads();
    float* mbuf = (float*)smem_us;
    float* lbuf = mbuf + 256;
    float* obuf = lbuf + 256;
    if (quad == 0) {
#pragma unroll
        for (int qf = 0; qf < 4; ++qf) {
            mbuf[wid * 64 + qf * 16 + col16] = m_state[qf];
            lbuf[wid * 64 + qf * 16 + col16] = l_state[qf];
        }
    }
#pragma unroll
    for (int mf = 0; mf < 4; ++mf)
#pragma unroll
        for (int nf = 0; nf < 2; ++nf)
#pragma unroll
            for (int i = 0; i < 4; ++i)
                obuf[wid * 2048 + (mf * 16 + quad * 4 + i) * 32 + nf * 16 + col16] =
                    acc_o[mf][nf][i];
    __syncthreads();
    {
        const int q = tid >> 2, dg = (tid & 3) * 8;
        float m0 = mbuf[q], m1 = mbuf[64 + q], m2 = mbuf[128 + q], m3 = mbuf[192 + q];
        float gm = fmaxf(fmaxf(m0, m1), fmaxf(m2, m3));
        float e0 = __expf(m0 - gm), e1 = __expf(m1 - gm);
        float e2 = __expf(m2 - gm), e3 = __expf(m3 - gm);
        float lt = lbuf[q] * e0 + lbuf[64 + q] * e1 + lbuf[128 + q] * e2 + lbuf[192 + q] * e3;
        float inv = 1.f / lt;
        const float* o0 = obuf + q * 32 + dg;
        float* orow = O + ((size_t)(b * LQv + qt * 64 + q)) * Cv + h * DHv + dg;
        float ov[8];
#pragma unroll
        for (int d = 0; d < 8; ++d)
            ov[d] = (o0[d] * e0 + o0[2048 + d] * e1 + o0[4096 + d] * e2 + o0[6144 + d] * e3) * inv;
        *(float4*)(orow) = make_float4(ov[0], ov[1], ov[2], ov[3]);
        *(float4*)(orow + 4) = make_float4(ov[4], ov[5], ov[6], ov[7]);
    }
}

// ---------------------------------------------------------------------------
// Deformable sampling over bf16 value. grid: B*LQ blocks, 256 thr = (h, d).
// offs+aw come MERGED in one [B*LQ][384] buffer: cols 0-255 offsets, 256-383 aw.
__global__ __launch_bounds__(256) void deform_sample(const unsigned short* __restrict__ value,
                                                     const float* __restrict__ oab,
                                                     const float* __restrict__ ref,
                                                     float* __restrict__ out) {
    const int bq = blockIdx.x;          // b*LQ + q
    const int b = bq >> 10;
    const int tid = threadIdx.x;
    const int h = tid >> 5, d = tid & 31;

    const float* aw = oab + (size_t)bq * 384 + 256 + h * 16;
    float w[16];
    float mx = -1e30f;
#pragma unroll
    for (int j = 0; j < 16; ++j) { w[j] = aw[j]; mx = fmaxf(mx, w[j]); }
    float ssum = 0.f;
#pragma unroll
    for (int j = 0; j < 16; ++j) { w[j] = __expf(w[j] - mx); ssum += w[j]; }
    float invs = 1.f / ssum;

    const float* op = oab + (size_t)bq * 384 + h * 32;
    const float* rp = ref + (size_t)bq * (Lv * 2);

    const int starts[4] = {0, 16384, 20480, 21504};
    const int WHl[4] = {128, 64, 32, 16};

    float acc = 0.f;
#pragma unroll 1
    for (int l = 0; l < 4; ++l) {
        const int wl = WHl[l];
        const float rx = rp[l * 2 + 0], ry = rp[l * 2 + 1];
        const unsigned short* vb0 = value + ((size_t)b * LSRCv + starts[l]) * Cv + h * DHv + d;
#pragma unroll 1
        for (int p = 0; p < 4; ++p) {
            float ox = op[l * 8 + p * 2 + 0], oy = op[l * 8 + p * 2 + 1];
            float x = rx * (float)wl + ox - 0.5f;
            float y = ry * (float)wl + oy - 0.5f;
            float fx0 = floorf(x), fy0 = floorf(y);
            int x0 = (int)fx0, y0 = (int)fy0;
            float tx = x - fx0, ty = y - fy0;
            float w00 = (1.f - tx) * (1.f - ty);
            float w10 = tx * (1.f - ty);
            float w01 = (1.f - tx) * ty;
            float w11 = tx * ty;
            float s = 0.f;
            bool xin0 = (x0 >= 0) & (x0 < wl);
            bool xin1 = (x0 + 1 >= 0) & (x0 + 1 < wl);
            bool yin0 = (y0 >= 0) & (y0 < wl);
            bool yin1 = (y0 + 1 >= 0) & (y0 + 1 < wl);
            if (yin0) {
                if (xin0) s = fmaf(w00, ubf2f(vb0[(size_t)(y0 * wl + x0) * Cv]), s);
                if (xin1) s = fmaf(w10, ubf2f(vb0[(size_t)(y0 * wl + x0 + 1) * Cv]), s);
            }
            if (yin1) {
                if (xin0) s = fmaf(w01, ubf2f(vb0[(size_t)((y0 + 1) * wl + x0) * Cv]), s);
                if (xin1) s = fmaf(w11, ubf2f(vb0[(size_t)((y0 + 1) * wl + x0 + 1) * Cv]), s);
            }
            acc = fmaf(w[l * 4 + p] * invs, s, acc);
        }
    }
    out[(size_t)bq * Cv + h * DHv + d] = acc;
}

// ---------------------------------------------------------------------------
// out = LayerNorm(x + r) * g + b    one block per row of 256
__global__ __launch_bounds__(256) void ln_residual(const float* __restrict__ x,
                                                   const float* __restrict__ r,
                                                   const float* __restrict__ g,
                                                   const float* __restrict__ bta,
                                                   float* __restrict__ out) {
    const int row = blockIdx.x;
    const int tid = threadIdx.x;
    float v = x[(size_t)row * Cv + tid] + r[(size_t)row * Cv + tid];
    float s = v, sq = v * v;
#pragma unroll
    for (int off = 32; off > 0; off >>= 1) {
        s  += __shfl_down(s, off, 64);
        sq += __shfl_down(sq, off, 64);
    }
    __shared__ float ss[4], sqq[4];
    int wid = tid >> 6;
    if ((tid & 63) == 0) { ss[wid] = s; sqq[wid] = sq; }
    __syncthreads();
    __shared__ float meansh, rstdsh;
    if (tid == 0) {
        float S = ss[0] + ss[1] + ss[2] + ss[3];
        float Q = sqq[0] + sqq[1] + sqq[2] + sqq[3];
        float mean = S * (1.f / Cv);
        float var = Q * (1.f / Cv) - mean * mean;
        meansh = mean;
        rstdsh = rsqrtf(var + 1e-5f);
    }
    __syncthreads();
    out[(size_t)row * Cv + tid] = (v - meansh) * rstdsh * g[tid] + bta[tid];
}

// ---------------------------------------------------------------------------
extern "C" void kernel_launch(void* const* d_in, const int* in_sizes, int n_in,
                              void* d_out, int out_size, void* d_ws, size_t ws_size,
                              hipStream_t stream) {
    const float* tgt       = (const float*)d_in[0];
    const float* query_pos = (const float*)d_in[1];
    const float* ref_pts   = (const float*)d_in[2];
    const float* src       = (const float*)d_in[3];
    const float* in_w      = (const float*)d_in[4];
    const float* in_b      = (const float*)d_in[5];
    const float* sa_w      = (const float*)d_in[6];
    const float* sa_b      = (const float*)d_in[7];
    const float* off_w     = (const float*)d_in[8];
    const float* off_b     = (const float*)d_in[9];
    const float* aw_w      = (const float*)d_in[10];
    const float* aw_b      = (const float*)d_in[11];
    const float* val_w     = (const float*)d_in[12];
    const float* val_b     = (const float*)d_in[13];
    const float* co_w      = (const float*)d_in[14];
    const float* co_b      = (const float*)d_in[15];
    const float* ln1_g     = (const float*)d_in[16];
    const float* ln1_b     = (const float*)d_in[17];
    const float* ln2_g     = (const float*)d_in[18];
    const float* ln2_b     = (const float*)d_in[19];
    const float* ln3_g     = (const float*)d_in[20];
    const float* ln3_b     = (const float*)d_in[21];
    const float* f1_w      = (const float*)d_in[22];
    const float* f1_b      = (const float*)d_in[23];
    const float* f2_w      = (const float*)d_in[24];
    const float* f2_b      = (const float*)d_in[25];

    const int M0  = Bv * LQv * Cv;          // 1048576
    const int VSZ = Bv * LSRCv * Cv;        // 22282240
    float* ws = (float*)d_ws;

    // Layout (all inside the VSZ-float "big" region + tail; total unchanged):
    //   big[0..2M)      qkbuf [4096][512]
    //   big[2M..3M)     vb
    //   big[3M..4M)     ob
    //   big[4M..15.2M)  value16 (VSZ ushorts) -- moved OUT of qkbuf overlap so
    //                   the value GEMM can run CONCURRENTLY with qk/v (v10).
    //   big[20M..20.5M) wb (bf16 weights), cbias after.
    float* big    = ws;
    float* qkbuf  = big;
    float* vb     = big + (size_t)2 * M0;
    float* ob     = big + (size_t)3 * M0;
    unsigned short* value16 = (unsigned short*)(big + (size_t)4 * M0);
    unsigned short* wb = (unsigned short*)(big + (size_t)20000000);
    float* cbias  = big + (size_t)20510000;           // 384 f32
    float* tgt_a  = ws + (size_t)VSZ;
    float* oabuf  = tgt_a + M0;             // [4096][384] merged offsets+aw
    float* sampled= oabuf + (size_t)Bv * LQv * 384;
    float* tgt_b  = sampled + M0;
    float* hidden = tgt_b + M0;             // B*LQ*DFF
    float* tmp    = hidden + (size_t)Bv * LQv * DFFv;

    // Fragment-shuffled bf16 weight segment offsets (ushort units)
    const size_t WB_IN = 0, WB_SA = 196608, WB_VAL = 262144, WB_OA = 327680,
                 WB_CO = 425984, WB_F1 = 491520, WB_F2 = 753664;

    const int Mq = Bv * LQv;                // 4096 rows
    dim3 blk256(256);

    // 0. pre-convert all weights to fragment-shuffled bf16 (one-time, ~2MB)
    cvt_weights<<<dim3(993), blk256, 0, stream>>>(
        in_w, sa_w, val_w, off_w, aw_w, co_w, f1_w, f2_w, off_b, aw_b, wb, cbias);

    // 1. FUSED dispatch: {qk proj (512 blk), v proj (256 blk), value proj
    //    (5440 blk)} — mutually independent; value-GEMM blocks fill the
    //    latency gaps of the small GEMMs. Replaces ~101 us of serial work.
    {
        GJob jqk = {tgt, query_pos, wb + WB_IN, in_b, qkbuf, nullptr,
                    Mq, 512, Cv, 0};
        GJob jv  = {tgt, nullptr, wb + WB_IN + 131072, in_b + 2 * Cv, vb, nullptr,
                    Mq, Cv, Cv, 0};
        GJob jval= {src, nullptr, wb + WB_VAL, val_b, nullptr, value16,
                    Bv * LSRCv, Cv, Cv, 0};
        const unsigned c0 = (Mq / 64) * (512 / 64);          // 512
        const unsigned c1 = (Mq / 64) * (Cv / 64);           // 256
        const unsigned c2 = ((Bv * LSRCv) / 64) * (Cv / 64); // 5440
        gemm_triple<<<dim3(c0 + c1 + c2), blk256, 0, stream>>>(
            jqk, jv, jval, c0, c0 + c1);
    }

    // 2. self-attention (MFMA flash; Q/K strided in qkbuf)
    attn_mfma<<<dim3(LQv / 64, Hv, Bv), blk256, 0, stream>>>(qkbuf, qkbuf + 256, vb, ob, 512);

    // 3. output projection, 4. LN2 residual
    gemm_single<<<dim3((Mq / 64) * (Cv / 64)), blk256, 0, stream>>>(
        ob, nullptr, wb + WB_SA, sa_b, tmp, nullptr, Cv, Cv, 0);
    ln_residual<<<dim3(Mq), blk256, 0, stream>>>(tgt, tmp, ln2_g, ln2_b, tgt_a);

    // 5. MERGED offsets + aw logits GEMM (N=384, fused add A = tgt_a + query_pos)
    gemm_single<<<dim3((Mq / 64) * (384 / 64)), blk256, 0, stream>>>(
        tgt_a, query_pos, wb + WB_OA, cbias, oabuf, nullptr, 384, Cv, 0);

    // 6. deformable bilinear sampling (bf16 value)
    deform_sample<<<dim3(Bv * LQv), blk256, 0, stream>>>(value16, oabuf, ref_pts, sampled);

    // 7. cross-attn output projection, 8. LN1 residual
    gemm_single<<<dim3((Mq / 64) * (Cv / 64)), blk256, 0, stream>>>(
        sampled, nullptr, wb + WB_CO, co_b, tmp, nullptr, Cv, Cv, 0);
    ln_residual<<<dim3(Mq), blk256, 0, stream>>>(tgt_a, tmp, ln1_g, ln1_b, tgt_b);

    // 9. FFN + LN3 -> d_out
    gemm_single<<<dim3((Mq / 64) * (DFFv / 64)), blk256, 0, stream>>>(
        tgt_b, nullptr, wb + WB_F1, f1_b, hidden, nullptr, DFFv, Cv, 1);
    gemm_single<<<dim3((Mq / 64) * (Cv / 64)), blk256, 0, stream>>>(
        hidden, nullptr, wb + WB_F2, f2_b, tmp, nullptr, Cv, DFFv, 0);
    ln_residual<<<dim3(Mq), blk256, 0, stream>>>(tgt_b, tmp, ln3_g, ln3_b, (float*)d_out);
}

// Round 10
// 349.395 us; speedup vs baseline: 1.0975x; 1.0378x over previous
//
#include <hip/hip_runtime.h>
#include <hip/hip_bf16.h>
#include <math.h>

// Problem constants
#define Bv   4
#define LQv  1024
#define Cv   256
#define Hv   8
#define Lv   4
#define Pv   4
#define DFFv 1024
#define DHv  32
#define LSRCv 21760   // 128*128 + 64*64 + 32*32 + 16*16

typedef __attribute__((ext_vector_type(8))) short bhalf8;   // 8 bf16 (4 VGPRs)
typedef __attribute__((ext_vector_type(4))) float floatx4;  // MFMA acc

// fp32 -> bf16 RNE, packed pair
__device__ inline unsigned pk_bf16x2(float x, float y) {
    unsigned xb = __float_as_uint(x), yb = __float_as_uint(y);
    unsigned xr = (xb + 0x7FFFu + ((xb >> 16) & 1u)) >> 16;
    unsigned yr = (yb + 0x7FFFu + ((yb >> 16) & 1u)) >> 16;
    return xr | (yr << 16);
}
__device__ inline unsigned short bf16_1(float x) {
    unsigned xb = __float_as_uint(x);
    return (unsigned short)((xb + 0x7FFFu + ((xb >> 16) & 1u)) >> 16);
}
__device__ inline float ubf2f(unsigned short u) {
    return __uint_as_float(((unsigned)u) << 16);
}

// ---------------------------------------------------------------------------
// Weight pre-conversion: f32 [N][K] -> bf16 in FRAGMENT-SHUFFLED layout so that
// in-GEMM B-fragment loads are 64-lane contiguous 1KB streams:
//   ushort index = ((n>>4)*(K>>5) + (k>>5))*512 + ((k>>3)&3)*128 + (n&15)*8 + (k&7)
// Segments (f32 offsets): in_w 0, sa_w 196608, val_w 262144,
// MERGED off_w+aw_w 327680 (N=384: off rows n=0..255, aw rows n=256..383),
// co_w 425984, f1_w 491520, f2_w 753664; total 1015808 f32.
// Block gridDim-1 additionally builds the concatenated off/aw bias (384 f32).
__global__ __launch_bounds__(256) void cvt_weights(const float* __restrict__ in_w,
                                                   const float* __restrict__ sa_w,
                                                   const float* __restrict__ val_w,
                                                   const float* __restrict__ off_w,
                                                   const float* __restrict__ aw_w,
                                                   const float* __restrict__ co_w,
                                                   const float* __restrict__ f1_w,
                                                   const float* __restrict__ f2_w,
                                                   const float* __restrict__ off_b,
                                                   const float* __restrict__ aw_b,
                                                   unsigned short* __restrict__ wp,
                                                   float* __restrict__ cbias) {
    const size_t idx4 = (size_t)blockIdx.x * 256 + threadIdx.x;   // float4 index
    if (idx4 >= 253952) {                                          // 1015808/4
        const int t = (int)(idx4 - 253952);
        if (t < 256) cbias[t] = off_b[t];
        else if (t < 384) cbias[t] = aw_b[t - 256];
        return;
    }
    const size_t f = idx4 * 4;
    const float* src; size_t off; int K; size_t obase; int nadd = 0;
    if (f < 196608)      { src = in_w;  off = f;          K = 256;  obase = 0; }
    else if (f < 262144) { src = sa_w;  off = f - 196608; K = 256;  obase = 196608; }
    else if (f < 327680) { src = val_w; off = f - 262144; K = 256;  obase = 262144; }
    else if (f < 393216) { src = off_w; off = f - 327680; K = 256;  obase = 327680; }
    else if (f < 425984) { src = aw_w;  off = f - 393216; K = 256;  obase = 327680; nadd = 256; }
    else if (f < 491520) { src = co_w;  off = f - 425984; K = 256;  obase = 425984; }
    else if (f < 753664) { src = f1_w;  off = f - 491520; K = 256;  obase = 491520; }
    else                 { src = f2_w;  off = f - 753664; K = 1024; obase = 753664; }
    float4 v = *(const float4*)(src + off);
    const int n = (int)(off / (size_t)K) + nadd, k = (int)(off % (size_t)K);
    const size_t di = obase + ((size_t)((n >> 4) * (K >> 5) + (k >> 5))) * 512
                    + (size_t)(((k >> 3) & 3) * 128 + (n & 15) * 8 + (k & 7));
    *(uint2*)(wp + di) = (uint2){pk_bf16x2(v.x, v.y), pk_bf16x2(v.z, v.w)};
}

// ---------------------------------------------------------------------------
// v8 GEMM body (proven) as device fn. 64x64 tile, BK=128, 4 waves, double-
// buffered LDS, drain-proof schedule, XCD-bijective swizzle, pre-shuffled W.
// Requirements: (M/64)%8==0, N%64==0, K%128==0.
struct GJob {
    const float* A; const float* A2;
    const unsigned short* Wp; const float* bias;
    float* Cf; unsigned short* Ch;
    int M, N, K, relu;
};

__device__ __forceinline__ void gemm_body(unsigned short* AsBase,   // 2 x 64*136
                                          const float* __restrict__ A,
                                          const float* __restrict__ A2,
                                          const unsigned short* __restrict__ Wp,
                                          const float* __restrict__ bias,
                                          float* __restrict__ Cf,
                                          unsigned short* __restrict__ Ch,
                                          int N, int K, int relu, unsigned bid) {
    const unsigned nc = (unsigned)N >> 6;
    const unsigned xcd = bid & 7, j = bid >> 3;
    const unsigned cpan = j % nc, r8 = j / nc;
    const int bm = (int)((xcd + (r8 << 3)) << 6);
    const int bn = (int)(cpan << 6);
    const int tid = threadIdx.x;
    const int wid = tid >> 6, lane = tid & 63;
    const int wr = wid >> 1, wc = wid & 1;       // wave tile: rows wr*32, cols wc*32
    const int col16 = lane & 15;
    const int quad = lane >> 4;

    const int srow0 = tid >> 4;            // 0..15
    const int scol = (tid & 15) * 4;       // 0..60
    const float* asrc = A + (size_t)(bm + srow0) * K + scol;
    const float* a2src = A2 ? A2 + (size_t)(bm + srow0) * K + scol : nullptr;

    const int K32 = K >> 5;
    const unsigned short* wbase = Wp + ((size_t)((bn >> 4) + wc * 2) * K32) * 512
                                + (size_t)lane * 8;

    floatx4 acc[2][2] = {};
    float4 rv[4][2];

    auto loadA = [&](int c) {
#pragma unroll
        for (int j2 = 0; j2 < 4; ++j2)
#pragma unroll
            for (int i = 0; i < 2; ++i)
                rv[j2][i] = *(const float4*)(asrc + (size_t)(16 * j2) * K + c * 128 + 64 * i);
        if (a2src) {
#pragma unroll
            for (int j2 = 0; j2 < 4; ++j2)
#pragma unroll
                for (int i = 0; i < 2; ++i) {
                    float4 t = *(const float4*)(a2src + (size_t)(16 * j2) * K + c * 128 + 64 * i);
                    rv[j2][i].x += t.x; rv[j2][i].y += t.y;
                    rv[j2][i].z += t.z; rv[j2][i].w += t.w;
                }
        }
    };
    auto writeA = [&](int buf) {
        unsigned short* dst = AsBase + buf * (64 * 136);
#pragma unroll
        for (int j2 = 0; j2 < 4; ++j2)
#pragma unroll
            for (int i = 0; i < 2; ++i) {
                uint2 p = {pk_bf16x2(rv[j2][i].x, rv[j2][i].y),
                           pk_bf16x2(rv[j2][i].z, rv[j2][i].w)};
                *(uint2*)&dst[(srow0 + 16 * j2) * 136 + scol + 64 * i] = p;
            }
    };

    const int NC = K >> 7;                 // chunks of 128
    loadA(0);
    writeA(0);

    for (int c = 0; c < NC; ++c) {
        __syncthreads();                    // buf[c&1] visible block-wide
        if (c + 1 < NC) loadA(c + 1);       // flies over the whole compute phase

        const unsigned short* ab = AsBase + (c & 1) * (64 * 136);
#pragma unroll
        for (int s = 0; s < 4; ++s) {
            bhalf8 bfr[2];
#pragma unroll
            for (int nt = 0; nt < 2; ++nt)
                bfr[nt] = *(const bhalf8*)(wbase + ((size_t)(nt * K32 + c * 4 + s)) * 512);
            bhalf8 af[2];
#pragma unroll
            for (int mt = 0; mt < 2; ++mt)
                af[mt] = *(const bhalf8*)&ab[(wr * 32 + mt * 16 + col16) * 136 + s * 32 + quad * 8];
#pragma unroll
            for (int mt = 0; mt < 2; ++mt)
#pragma unroll
                for (int nt = 0; nt < 2; ++nt)
                    acc[mt][nt] = __builtin_amdgcn_mfma_f32_16x16x32_bf16(
                        af[mt], bfr[nt], acc[mt][nt], 0, 0, 0);
        }

        if (c + 1 < NC) writeA((c + 1) & 1);  // per-wave vmcnt wait only, no barrier
    }

#pragma unroll
    for (int mt = 0; mt < 2; ++mt) {
#pragma unroll
        for (int nt = 0; nt < 2; ++nt) {
            const int col = bn + wc * 32 + nt * 16 + col16;
            const float bv = bias[col];
#pragma unroll
            for (int i = 0; i < 4; ++i) {
                const int row = bm + wr * 32 + mt * 16 + quad * 4 + i;
                float v = acc[mt][nt][i] + bv;
                if (relu) v = fmaxf(v, 0.f);
                if (Ch) Ch[(size_t)row * N + col] = bf16_1(v);
                else    Cf[(size_t)row * N + col] = v;
            }
        }
    }
}

__global__ __launch_bounds__(256, 4) void gemm_single(const float* __restrict__ A,
                                                      const float* __restrict__ A2,
                                                      const unsigned short* __restrict__ Wp,
                                                      const float* __restrict__ bias,
                                                      float* __restrict__ Cf,
                                                      unsigned short* __restrict__ Ch,
                                                      int N, int K, int relu) {
    __shared__ __attribute__((aligned(16))) unsigned short As[2 * 64 * 136]; // 34816 B
    gemm_body(As, A, A2, Wp, bias, Cf, Ch, N, K, relu, blockIdx.x);
}

// Three independent GEMMs in ONE dispatch: blocks [0,c0) run j0, [c0,c01) j1,
// [c01,grid) j2. Fills latency gaps of small GEMMs with big-GEMM blocks.
__global__ __launch_bounds__(256, 4) void gemm_triple(GJob j0, GJob j1, GJob j2,
                                                      unsigned c0, unsigned c01) {
    __shared__ __attribute__((aligned(16))) unsigned short As[2 * 64 * 136]; // 34816 B
    const unsigned b = blockIdx.x;
    if (b < c0) {
        gemm_body(As, j0.A, j0.A2, j0.Wp, j0.bias, j0.Cf, j0.Ch, j0.N, j0.K, j0.relu, b);
    } else if (b < c01) {
        gemm_body(As, j1.A, j1.A2, j1.Wp, j1.bias, j1.Cf, j1.Ch, j1.N, j1.K, j1.relu, b - c0);
    } else {
        gemm_body(As, j2.A, j2.A2, j2.Wp, j2.bias, j2.Cf, j2.Ch, j2.N, j2.K, j2.relu, b - c01);
    }
}

// ---------------------------------------------------------------------------
// v11: GEMM + residual + LayerNorm FUSED. N=256 fixed; block = 32 rows x 256
// cols (4 waves = 4 col panels of 64). out = LN(res + A@W^T + bias)*g + beta.
// After the K loop the whole LN row lives in the block: quad shfl_xor reduce
// (16 lanes/row-slice) -> cross-wave reduce through the dead LDS A-buffer ->
// normalize in-register -> write final tensor. Removes the ln_residual
// dispatch and the 8 MB tmp round-trip per pair. K%128==0 (256 or 1024).
__global__ __launch_bounds__(256, 2) void gemm_ln(const float* __restrict__ A,
                                                  const unsigned short* __restrict__ Wp,
                                                  const float* __restrict__ bias,
                                                  const float* __restrict__ res,
                                                  const float* __restrict__ g,
                                                  const float* __restrict__ beta,
                                                  float* __restrict__ out,
                                                  int K) {
    __shared__ __attribute__((aligned(16))) unsigned short As[2][32 * 136]; // 17408 B
    const int bm = blockIdx.x * 32;
    const int tid = threadIdx.x;
    const int wid = tid >> 6, lane = tid & 63;
    const int col16 = lane & 15, quad = lane >> 4;
    const int wc = wid;                    // wave col panel: cols wc*64

    // staging: thread covers row tid>>3 (0..31), f32 cols (tid&7)*16 .. +16
    const int srow = tid >> 3;
    const int sc16 = (tid & 7) * 16;
    const float* asrc = A + (size_t)(bm + srow) * K + sc16;

    const int K32 = K >> 5;
    const unsigned short* wbase = Wp + (size_t)(wc * 4) * K32 * 512 + (size_t)lane * 8;

    floatx4 acc[2][4] = {};                // [mt][nt]
    float4 rv[4];

    auto loadA = [&](int c) {
#pragma unroll
        for (int j = 0; j < 4; ++j)
            rv[j] = *(const float4*)(asrc + c * 128 + j * 4);
    };
    auto writeA = [&](int buf) {
#pragma unroll
        for (int j = 0; j < 4; ++j) {
            uint2 p = {pk_bf16x2(rv[j].x, rv[j].y), pk_bf16x2(rv[j].z, rv[j].w)};
            *(uint2*)&As[buf][srow * 136 + sc16 + j * 4] = p;
        }
    };

    const int NC = K >> 7;
    loadA(0);
    writeA(0);

    for (int c = 0; c < NC; ++c) {
        __syncthreads();
        if (c + 1 < NC) loadA(c + 1);

        const unsigned short* ab = As[c & 1];
#pragma unroll
        for (int s = 0; s < 4; ++s) {
            bhalf8 bfr[4];
#pragma unroll
            for (int nt = 0; nt < 4; ++nt)
                bfr[nt] = *(const bhalf8*)(wbase + ((size_t)(nt * K32 + c * 4 + s)) * 512);
            bhalf8 af[2];
#pragma unroll
            for (int mt = 0; mt < 2; ++mt)
                af[mt] = *(const bhalf8*)&ab[(mt * 16 + col16) * 136 + s * 32 + quad * 8];
#pragma unroll
            for (int mt = 0; mt < 2; ++mt)
#pragma unroll
                for (int nt = 0; nt < 4; ++nt)
                    acc[mt][nt] = __builtin_amdgcn_mfma_f32_16x16x32_bf16(
                        af[mt], bfr[nt], acc[mt][nt], 0, 0, 0);
        }

        if (c + 1 < NC) writeA((c + 1) & 1);
    }

    // ---- fused epilogue: bias + residual, stats, LN, write
    float bias_r[4];
#pragma unroll
    for (int nt = 0; nt < 4; ++nt) bias_r[nt] = bias[wc * 64 + nt * 16 + col16];

    float s_[2][4], q_[2][4];
#pragma unroll
    for (int mt = 0; mt < 2; ++mt)
#pragma unroll
        for (int i = 0; i < 4; ++i) { s_[mt][i] = 0.f; q_[mt][i] = 0.f; }

#pragma unroll
    for (int mt = 0; mt < 2; ++mt)
#pragma unroll
        for (int i = 0; i < 4; ++i) {
            const int row = bm + mt * 16 + quad * 4 + i;
#pragma unroll
            for (int nt = 0; nt < 4; ++nt) {
                float r = res[(size_t)row * 256 + wc * 64 + nt * 16 + col16];
                float v = acc[mt][nt][i] + bias_r[nt] + r;
                acc[mt][nt][i] = v;
                s_[mt][i] += v;
                q_[mt][i] = fmaf(v, v, q_[mt][i]);
            }
        }

    // reduce over the 16 lanes (col16) of each quad
#pragma unroll
    for (int mt = 0; mt < 2; ++mt)
#pragma unroll
        for (int i = 0; i < 4; ++i) {
#pragma unroll
            for (int off = 1; off < 16; off <<= 1) {
                s_[mt][i] += __shfl_xor(s_[mt][i], off, 64);
                q_[mt][i] += __shfl_xor(q_[mt][i], off, 64);
            }
        }

    __syncthreads();                       // all As reads done; reuse as scratch
    float* red = (float*)As;               // sums [4][32], sqs +128, mean +256, rstd +288
    if (col16 == 0) {
#pragma unroll
        for (int mt = 0; mt < 2; ++mt)
#pragma unroll
            for (int i = 0; i < 4; ++i) {
                red[wid * 32 + mt * 16 + quad * 4 + i] = s_[mt][i];
                red[128 + wid * 32 + mt * 16 + quad * 4 + i] = q_[mt][i];
            }
    }
    __syncthreads();
    float* mean_s = red + 256;
    float* rstd_s = red + 288;
    if (tid < 32) {
        float S = red[tid] + red[32 + tid] + red[64 + tid] + red[96 + tid];
        float Q = red[128 + tid] + red[160 + tid] + red[192 + tid] + red[224 + tid];
        float mean = S * (1.f / 256.f);
        float var = Q * (1.f / 256.f) - mean * mean;
        mean_s[tid] = mean;
        rstd_s[tid] = rsqrtf(var + 1e-5f);
    }
    __syncthreads();

    float g_r[4], b_r[4];
#pragma unroll
    for (int nt = 0; nt < 4; ++nt) {
        g_r[nt] = g[wc * 64 + nt * 16 + col16];
        b_r[nt] = beta[wc * 64 + nt * 16 + col16];
    }
#pragma unroll
    for (int mt = 0; mt < 2; ++mt)
#pragma unroll
        for (int i = 0; i < 4; ++i) {
            const int rl = mt * 16 + quad * 4 + i;
            const float mn = mean_s[rl], rs = rstd_s[rl];
#pragma unroll
            for (int nt = 0; nt < 4; ++nt)
                out[(size_t)(bm + rl) * 256 + wc * 64 + nt * 16 + col16] =
                    (acc[mt][nt][i] - mn) * rs * g_r[nt] + b_r[nt];
        }
}

// ---------------------------------------------------------------------------
// MFMA flash self-attention. grid (LQ/64, H, B), block 256 = 4 waves.
// Q/K read with configurable row stride (they live in one [M,512] buffer).
#define ATT_SCALE 0.17677669529663687f
__global__ __launch_bounds__(256, 2) void attn_mfma(const float* __restrict__ Q,
                                                    const float* __restrict__ Kb,
                                                    const float* __restrict__ Vb,
                                                    float* __restrict__ O,
                                                    int qk_stride) {
    const int b = blockIdx.z, h = blockIdx.y, qt = blockIdx.x;
    const int tid = threadIdx.x;
    const int wid = tid >> 6, lane = tid & 63;
    const int col16 = lane & 15, quad = lane >> 4;

    __shared__ unsigned short smem_us[40960];
    unsigned short* Ks = smem_us + wid * 9600;
    unsigned short* Vt = Ks + 2560;
    unsigned short* Ps = Ks + 4864;
    float* corr_s = (float*)(Ks + 9472);
    unsigned short* Qs = smem_us + 38400;

    // ---- stage Q (scaled) once, whole block
    {
        const int row = tid >> 2, part = tid & 3;
        const float* qsrc = Q + ((size_t)(b * LQv + qt * 64 + row)) * qk_stride + h * DHv + part * 8;
        float4 qa = *(const float4*)qsrc;
        float4 qb2 = *(const float4*)(qsrc + 4);
        uint4 qp = {pk_bf16x2(qa.x * ATT_SCALE, qa.y * ATT_SCALE),
                    pk_bf16x2(qa.z * ATT_SCALE, qa.w * ATT_SCALE),
                    pk_bf16x2(qb2.x * ATT_SCALE, qb2.y * ATT_SCALE),
                    pk_bf16x2(qb2.z * ATT_SCALE, qb2.w * ATT_SCALE)};
        *(uint4*)&Qs[row * 40 + part * 8] = qp;
    }
    __syncthreads();
    bhalf8 qfr[4];
#pragma unroll
    for (int j = 0; j < 4; ++j)
        qfr[j] = *(const bhalf8*)&Qs[(j * 16 + col16) * 40 + quad * 8];

    float m_state[4] = {-1e30f, -1e30f, -1e30f, -1e30f};
    float l_state[4] = {0.f, 0.f, 0.f, 0.f};
    floatx4 acc_o[4][2] = {};
    const int dd = lane & 31, half = lane >> 5;

    const float* kbase = Kb + ((size_t)(b * LQv + wid * 256)) * qk_stride + h * DHv;
    const float* vbase = Vb + ((size_t)(b * LQv + wid * 256)) * Cv + h * DHv;

#pragma unroll 1
    for (int t = 0; t < 4; ++t) {
        {
            const float* ks = kbase + (size_t)(t * 64 + lane) * qk_stride;
            float4 f0 = *(const float4*)(ks + 0),  f1 = *(const float4*)(ks + 4);
            float4 f2 = *(const float4*)(ks + 8),  f3 = *(const float4*)(ks + 12);
            float4 f4 = *(const float4*)(ks + 16), f5 = *(const float4*)(ks + 20);
            float4 f6 = *(const float4*)(ks + 24), f7 = *(const float4*)(ks + 28);
            uint4 p0 = {pk_bf16x2(f0.x, f0.y), pk_bf16x2(f0.z, f0.w),
                        pk_bf16x2(f1.x, f1.y), pk_bf16x2(f1.z, f1.w)};
            uint4 p1 = {pk_bf16x2(f2.x, f2.y), pk_bf16x2(f2.z, f2.w),
                        pk_bf16x2(f3.x, f3.y), pk_bf16x2(f3.z, f3.w)};
            uint4 p2 = {pk_bf16x2(f4.x, f4.y), pk_bf16x2(f4.z, f4.w),
                        pk_bf16x2(f5.x, f5.y), pk_bf16x2(f5.z, f5.w)};
            uint4 p3 = {pk_bf16x2(f6.x, f6.y), pk_bf16x2(f6.z, f6.w),
                        pk_bf16x2(f7.x, f7.y), pk_bf16x2(f7.z, f7.w)};
            *(uint4*)&Ks[lane * 40 + 0]  = p0;
            *(uint4*)&Ks[lane * 40 + 8]  = p1;
            *(uint4*)&Ks[lane * 40 + 16] = p2;
            *(uint4*)&Ks[lane * 40 + 24] = p3;
        }
        {
            const float* vs = vbase + (size_t)(t * 64 + half * 32) * Cv + dd;
#pragma unroll
            for (int j4 = 0; j4 < 8; ++j4) {
                float g0 = vs[(j4 * 4 + 0) * Cv], g1 = vs[(j4 * 4 + 1) * Cv];
                float g2 = vs[(j4 * 4 + 2) * Cv], g3 = vs[(j4 * 4 + 3) * Cv];
                uint2 vp = {pk_bf16x2(g0, g1), pk_bf16x2(g2, g3)};
                *(uint2*)&Vt[dd * 72 + half * 32 + j4 * 4] = vp;
            }
        }

        floatx4 accs[4][4] = {};
        bhalf8 af[4];
#pragma unroll
        for (int kf = 0; kf < 4; ++kf)
            af[kf] = *(const bhalf8*)&Ks[(kf * 16 + col16) * 40 + quad * 8];
#pragma unroll
        for (int kf = 0; kf < 4; ++kf)
#pragma unroll
            for (int qf = 0; qf < 4; ++qf)
                accs[kf][qf] = __builtin_amdgcn_mfma_f32_16x16x32_bf16(
                    af[kf], qfr[qf], accs[kf][qf], 0, 0, 0);

#pragma unroll
        for (int qf = 0; qf < 4; ++qf) {
            float tmax = -1e30f;
#pragma unroll
            for (int kf = 0; kf < 4; ++kf) {
                tmax = fmaxf(tmax, fmaxf(fmaxf(accs[kf][qf][0], accs[kf][qf][1]),
                                         fmaxf(accs[kf][qf][2], accs[kf][qf][3])));
            }
            tmax = fmaxf(tmax, __shfl_xor(tmax, 16));
            tmax = fmaxf(tmax, __shfl_xor(tmax, 32));
            float mnew = fmaxf(m_state[qf], tmax);
            float cr = __expf(m_state[qf] - mnew);
            m_state[qf] = mnew;
            float psum = 0.f;
#pragma unroll
            for (int kf = 0; kf < 4; ++kf) {
                float p0 = __expf(accs[kf][qf][0] - mnew);
                float p1 = __expf(accs[kf][qf][1] - mnew);
                float p2 = __expf(accs[kf][qf][2] - mnew);
                float p3 = __expf(accs[kf][qf][3] - mnew);
                psum += (p0 + p1) + (p2 + p3);
                uint2 pp = {pk_bf16x2(p0, p1), pk_bf16x2(p2, p3)};
                *(uint2*)&Ps[(qf * 16 + col16) * 72 + kf * 16 + quad * 4] = pp;
            }
            psum += __shfl_xor(psum, 16);
            psum += __shfl_xor(psum, 32);
            l_state[qf] = l_state[qf] * cr + psum;
            if (quad == 0) corr_s[qf * 16 + col16] = cr;
        }

#pragma unroll
        for (int mf = 0; mf < 4; ++mf) {
            float4 cv = *(const float4*)&corr_s[mf * 16 + quad * 4];
#pragma unroll
            for (int nf = 0; nf < 2; ++nf) {
                acc_o[mf][nf][0] *= cv.x;
                acc_o[mf][nf][1] *= cv.y;
                acc_o[mf][nf][2] *= cv.z;
                acc_o[mf][nf][3] *= cv.w;
            }
        }
#pragma unroll
        for (int ks2 = 0; ks2 < 2; ++ks2) {
            bhalf8 pf[4], vf[2];
#pragma unroll
            for (int mf = 0; mf < 4; ++mf)
                pf[mf] = *(const bhalf8*)&Ps[(mf * 16 + col16) * 72 + ks2 * 32 + quad * 8];
#pragma unroll
            for (int nf = 0; nf < 2; ++nf)
                vf[nf] = *(const bhalf8*)&Vt[(nf * 16 + col16) * 72 + ks2 * 32 + quad * 8];
#pragma unroll
            for (int mf = 0; mf < 4; ++mf)
#pragma unroll
                for (int nf = 0; nf < 2; ++nf)
                    acc_o[mf][nf] = __builtin_amdgcn_mfma_f32_16x16x32_bf16(
                        pf[mf], vf[nf], acc_o[mf][nf], 0, 0, 0);
        }
    }

    __syncthreads();
    float* mbuf = (float*)smem_us;
    float* lbuf = mbuf + 256;
    float* obuf = lbuf + 256;
    if (quad == 0) {
#pragma unroll
        for (int qf = 0; qf < 4; ++qf) {
            mbuf[wid * 64 + qf * 16 + col16] = m_state[qf];
            lbuf[wid * 64 + qf * 16 + col16] = l_state[qf];
        }
    }
#pragma unroll
    for (int mf = 0; mf < 4; ++mf)
#pragma unroll
        for (int nf = 0; nf < 2; ++nf)
#pragma unroll
            for (int i = 0; i < 4; ++i)
                obuf[wid * 2048 + (mf * 16 + quad * 4 + i) * 32 + nf * 16 + col16] =
                    acc_o[mf][nf][i];
    __syncthreads();
    {
        const int q = tid >> 2, dg = (tid & 3) * 8;
        float m0 = mbuf[q], m1 = mbuf[64 + q], m2 = mbuf[128 + q], m3 = mbuf[192 + q];
        float gm = fmaxf(fmaxf(m0, m1), fmaxf(m2, m3));
        float e0 = __expf(m0 - gm), e1 = __expf(m1 - gm);
        float e2 = __expf(m2 - gm), e3 = __expf(m3 - gm);
        float lt = lbuf[q] * e0 + lbuf[64 + q] * e1 + lbuf[128 + q] * e2 + lbuf[192 + q] * e3;
        float inv = 1.f / lt;
        const float* o0 = obuf + q * 32 + dg;
        float* orow = O + ((size_t)(b * LQv + qt * 64 + q)) * Cv + h * DHv + dg;
        float ov[8];
#pragma unroll
        for (int d = 0; d < 8; ++d)
            ov[d] = (o0[d] * e0 + o0[2048 + d] * e1 + o0[4096 + d] * e2 + o0[6144 + d] * e3) * inv;
        *(float4*)(orow) = make_float4(ov[0], ov[1], ov[2], ov[3]);
        *(float4*)(orow + 4) = make_float4(ov[4], ov[5], ov[6], ov[7]);
    }
}

// ---------------------------------------------------------------------------
// Deformable sampling over bf16 value. grid: B*LQ blocks, 256 thr = (h, d).
// offs+aw come MERGED in one [B*LQ][384] buffer: cols 0-255 offsets, 256-383 aw.
__global__ __launch_bounds__(256) void deform_sample(const unsigned short* __restrict__ value,
                                                     const float* __restrict__ oab,
                                                     const float* __restrict__ ref,
                                                     float* __restrict__ out) {
    const int bq = blockIdx.x;          // b*LQ + q
    const int b = bq >> 10;
    const int tid = threadIdx.x;
    const int h = tid >> 5, d = tid & 31;

    const float* aw = oab + (size_t)bq * 384 + 256 + h * 16;
    float w[16];
    float mx = -1e30f;
#pragma unroll
    for (int j = 0; j < 16; ++j) { w[j] = aw[j]; mx = fmaxf(mx, w[j]); }
    float ssum = 0.f;
#pragma unroll
    for (int j = 0; j < 16; ++j) { w[j] = __expf(w[j] - mx); ssum += w[j]; }
    float invs = 1.f / ssum;

    const float* op = oab + (size_t)bq * 384 + h * 32;
    const float* rp = ref + (size_t)bq * (Lv * 2);

    const int starts[4] = {0, 16384, 20480, 21504};
    const int WHl[4] = {128, 64, 32, 16};

    float acc = 0.f;
#pragma unroll 1
    for (int l = 0; l < 4; ++l) {
        const int wl = WHl[l];
        const float rx = rp[l * 2 + 0], ry = rp[l * 2 + 1];
        const unsigned short* vb0 = value + ((size_t)b * LSRCv + starts[l]) * Cv + h * DHv + d;
#pragma unroll 1
        for (int p = 0; p < 4; ++p) {
            float ox = op[l * 8 + p * 2 + 0], oy = op[l * 8 + p * 2 + 1];
            float x = rx * (float)wl + ox - 0.5f;
            float y = ry * (float)wl + oy - 0.5f;
            float fx0 = floorf(x), fy0 = floorf(y);
            int x0 = (int)fx0, y0 = (int)fy0;
            float tx = x - fx0, ty = y - fy0;
            float w00 = (1.f - tx) * (1.f - ty);
            float w10 = tx * (1.f - ty);
            float w01 = (1.f - tx) * ty;
            float w11 = tx * ty;
            float s = 0.f;
            bool xin0 = (x0 >= 0) & (x0 < wl);
            bool xin1 = (x0 + 1 >= 0) & (x0 + 1 < wl);
            bool yin0 = (y0 >= 0) & (y0 < wl);
            bool yin1 = (y0 + 1 >= 0) & (y0 + 1 < wl);
            if (yin0) {
                if (xin0) s = fmaf(w00, ubf2f(vb0[(size_t)(y0 * wl + x0) * Cv]), s);
                if (xin1) s = fmaf(w10, ubf2f(vb0[(size_t)(y0 * wl + x0 + 1) * Cv]), s);
            }
            if (yin1) {
                if (xin0) s = fmaf(w01, ubf2f(vb0[(size_t)((y0 + 1) * wl + x0) * Cv]), s);
                if (xin1) s = fmaf(w11, ubf2f(vb0[(size_t)((y0 + 1) * wl + x0 + 1) * Cv]), s);
            }
            acc = fmaf(w[l * 4 + p] * invs, s, acc);
        }
    }
    out[(size_t)bq * Cv + h * DHv + d] = acc;
}

// ---------------------------------------------------------------------------
extern "C" void kernel_launch(void* const* d_in, const int* in_sizes, int n_in,
                              void* d_out, int out_size, void* d_ws, size_t ws_size,
                              hipStream_t stream) {
    const float* tgt       = (const float*)d_in[0];
    const float* query_pos = (const float*)d_in[1];
    const float* ref_pts   = (const float*)d_in[2];
    const float* src       = (const float*)d_in[3];
    const float* in_w      = (const float*)d_in[4];
    const float* in_b      = (const float*)d_in[5];
    const float* sa_w      = (const float*)d_in[6];
    const float* sa_b      = (const float*)d_in[7];
    const float* off_w     = (const float*)d_in[8];
    const float* off_b     = (const float*)d_in[9];
    const float* aw_w      = (const float*)d_in[10];
    const float* aw_b      = (const float*)d_in[11];
    const float* val_w     = (const float*)d_in[12];
    const float* val_b     = (const float*)d_in[13];
    const float* co_w      = (const float*)d_in[14];
    const float* co_b      = (const float*)d_in[15];
    const float* ln1_g     = (const float*)d_in[16];
    const float* ln1_b     = (const float*)d_in[17];
    const float* ln2_g     = (const float*)d_in[18];
    const float* ln2_b     = (const float*)d_in[19];
    const float* ln3_g     = (const float*)d_in[20];
    const float* ln3_b     = (const float*)d_in[21];
    const float* f1_w      = (const float*)d_in[22];
    const float* f1_b      = (const float*)d_in[23];
    const float* f2_w      = (const float*)d_in[24];
    const float* f2_b      = (const float*)d_in[25];

    const int M0  = Bv * LQv * Cv;          // 1048576
    const int VSZ = Bv * LSRCv * Cv;        // 22282240
    float* ws = (float*)d_ws;

    // Layout:
    //   big[0..2M)      qkbuf [4096][512]
    //   big[2M..3M)     vb
    //   big[3M..4M)     ob
    //   big[4M..15.2M)  value16 (VSZ ushorts) — disjoint from qkbuf so the
    //                   value GEMM runs concurrently with qk/v (v10).
    //   big[20M..20.5M) wb (bf16 weights), cbias after.
    float* big    = ws;
    float* qkbuf  = big;
    float* vb     = big + (size_t)2 * M0;
    float* ob     = big + (size_t)3 * M0;
    unsigned short* value16 = (unsigned short*)(big + (size_t)4 * M0);
    unsigned short* wb = (unsigned short*)(big + (size_t)20000000);
    float* cbias  = big + (size_t)20510000;           // 384 f32
    float* tgt_a  = ws + (size_t)VSZ;
    float* oabuf  = tgt_a + M0;             // [4096][384] merged offsets+aw
    float* sampled= oabuf + (size_t)Bv * LQv * 384;
    float* tgt_b  = sampled + M0;
    float* hidden = tgt_b + M0;             // B*LQ*DFF

    // Fragment-shuffled bf16 weight segment offsets (ushort units)
    const size_t WB_IN = 0, WB_SA = 196608, WB_VAL = 262144, WB_OA = 327680,
                 WB_CO = 425984, WB_F1 = 491520, WB_F2 = 753664;

    const int Mq = Bv * LQv;                // 4096 rows
    dim3 blk256(256);

    // 0. pre-convert all weights to fragment-shuffled bf16 (one-time, ~2MB)
    cvt_weights<<<dim3(993), blk256, 0, stream>>>(
        in_w, sa_w, val_w, off_w, aw_w, co_w, f1_w, f2_w, off_b, aw_b, wb, cbias);

    // 1. FUSED dispatch: {qk proj, v proj, value proj} — mutually independent.
    {
        GJob jqk = {tgt, query_pos, wb + WB_IN, in_b, qkbuf, nullptr,
                    Mq, 512, Cv, 0};
        GJob jv  = {tgt, nullptr, wb + WB_IN + 131072, in_b + 2 * Cv, vb, nullptr,
                    Mq, Cv, Cv, 0};
        GJob jval= {src, nullptr, wb + WB_VAL, val_b, nullptr, value16,
                    Bv * LSRCv, Cv, Cv, 0};
        const unsigned c0 = (Mq / 64) * (512 / 64);          // 512
        const unsigned c1 = (Mq / 64) * (Cv / 64);           // 256
        const unsigned c2 = ((Bv * LSRCv) / 64) * (Cv / 64); // 5440
        gemm_triple<<<dim3(c0 + c1 + c2), blk256, 0, stream>>>(
            jqk, jv, jval, c0, c0 + c1);
    }

    // 2. self-attention (MFMA flash; Q/K strided in qkbuf)
    attn_mfma<<<dim3(LQv / 64, Hv, Bv), blk256, 0, stream>>>(qkbuf, qkbuf + 256, vb, ob, 512);

    // 3. FUSED sa-projection + LN2: tgt_a = LN(tgt + ob@sa_w^T + sa_b)
    gemm_ln<<<dim3(Mq / 32), blk256, 0, stream>>>(
        ob, wb + WB_SA, sa_b, tgt, ln2_g, ln2_b, tgt_a, Cv);

    // 4. MERGED offsets + aw logits GEMM (N=384, fused add A = tgt_a + query_pos)
    gemm_single<<<dim3((Mq / 64) * (384 / 64)), blk256, 0, stream>>>(
        tgt_a, query_pos, wb + WB_OA, cbias, oabuf, nullptr, 384, Cv, 0);

    // 5. deformable bilinear sampling (bf16 value)
    deform_sample<<<dim3(Bv * LQv), blk256, 0, stream>>>(value16, oabuf, ref_pts, sampled);

    // 6. FUSED cross-attn projection + LN1: tgt_b = LN(tgt_a + sampled@co_w^T + co_b)
    gemm_ln<<<dim3(Mq / 32), blk256, 0, stream>>>(
        sampled, wb + WB_CO, co_b, tgt_a, ln1_g, ln1_b, tgt_b, Cv);

    // 7. FFN up (relu)
    gemm_single<<<dim3((Mq / 64) * (DFFv / 64)), blk256, 0, stream>>>(
        tgt_b, nullptr, wb + WB_F1, f1_b, hidden, nullptr, DFFv, Cv, 1);

    // 8. FUSED FFN down + LN3 -> d_out
    gemm_ln<<<dim3(Mq / 32), blk256, 0, stream>>>(
        hidden, wb + WB_F2, f2_b, tgt_b, ln3_g, ln3_b, (float*)d_out, DFFv);
}

// Round 12
// 347.788 us; speedup vs baseline: 1.1025x; 1.0046x over previous
//
#include <hip/hip_runtime.h>
#include <hip/hip_bf16.h>
#include <math.h>

// Problem constants
#define Bv   4
#define LQv  1024
#define Cv   256
#define Hv   8
#define Lv   4
#define Pv   4
#define DFFv 1024
#define DHv  32
#define LSRCv 21760   // 128*128 + 64*64 + 32*32 + 16*16

typedef __attribute__((ext_vector_type(8))) short bhalf8;   // 8 bf16 (4 VGPRs)
typedef __attribute__((ext_vector_type(4))) float floatx4;  // MFMA acc

// fp32 -> bf16 RNE, packed pair
__device__ inline unsigned pk_bf16x2(float x, float y) {
    unsigned xb = __float_as_uint(x), yb = __float_as_uint(y);
    unsigned xr = (xb + 0x7FFFu + ((xb >> 16) & 1u)) >> 16;
    unsigned yr = (yb + 0x7FFFu + ((yb >> 16) & 1u)) >> 16;
    return xr | (yr << 16);
}
__device__ inline unsigned short bf16_1(float x) {
    unsigned xb = __float_as_uint(x);
    return (unsigned short)((xb + 0x7FFFu + ((xb >> 16) & 1u)) >> 16);
}
__device__ inline float ubf2f(unsigned short u) {
    return __uint_as_float(((unsigned)u) << 16);
}

// ---------------------------------------------------------------------------
// Weight pre-conversion: f32 [N][K] -> bf16 in FRAGMENT-SHUFFLED layout so that
// in-GEMM B-fragment loads are 64-lane contiguous 1KB streams:
//   ushort index = ((n>>4)*(K>>5) + (k>>5))*512 + ((k>>3)&3)*128 + (n&15)*8 + (k&7)
// Segments (f32 offsets): in_w 0, sa_w 196608, val_w 262144,
// MERGED off_w+aw_w 327680 (N=384: off rows n=0..255, aw rows n=256..383),
// co_w 425984, f1_w 491520, f2_w 753664; total 1015808 f32.
// Block gridDim-1 additionally builds the concatenated off/aw bias (384 f32).
__global__ __launch_bounds__(256) void cvt_weights(const float* __restrict__ in_w,
                                                   const float* __restrict__ sa_w,
                                                   const float* __restrict__ val_w,
                                                   const float* __restrict__ off_w,
                                                   const float* __restrict__ aw_w,
                                                   const float* __restrict__ co_w,
                                                   const float* __restrict__ f1_w,
                                                   const float* __restrict__ f2_w,
                                                   const float* __restrict__ off_b,
                                                   const float* __restrict__ aw_b,
                                                   unsigned short* __restrict__ wp,
                                                   float* __restrict__ cbias) {
    const size_t idx4 = (size_t)blockIdx.x * 256 + threadIdx.x;   // float4 index
    if (idx4 >= 253952) {                                          // 1015808/4
        const int t = (int)(idx4 - 253952);
        if (t < 256) cbias[t] = off_b[t];
        else if (t < 384) cbias[t] = aw_b[t - 256];
        return;
    }
    const size_t f = idx4 * 4;
    const float* src; size_t off; int K; size_t obase; int nadd = 0;
    if (f < 196608)      { src = in_w;  off = f;          K = 256;  obase = 0; }
    else if (f < 262144) { src = sa_w;  off = f - 196608; K = 256;  obase = 196608; }
    else if (f < 327680) { src = val_w; off = f - 262144; K = 256;  obase = 262144; }
    else if (f < 393216) { src = off_w; off = f - 327680; K = 256;  obase = 327680; }
    else if (f < 425984) { src = aw_w;  off = f - 393216; K = 256;  obase = 327680; nadd = 256; }
    else if (f < 491520) { src = co_w;  off = f - 425984; K = 256;  obase = 425984; }
    else if (f < 753664) { src = f1_w;  off = f - 491520; K = 256;  obase = 491520; }
    else                 { src = f2_w;  off = f - 753664; K = 1024; obase = 753664; }
    float4 v = *(const float4*)(src + off);
    const int n = (int)(off / (size_t)K) + nadd, k = (int)(off % (size_t)K);
    const size_t di = obase + ((size_t)((n >> 4) * (K >> 5) + (k >> 5))) * 512
                    + (size_t)(((k >> 3) & 3) * 128 + (n & 15) * 8 + (k & 7));
    *(uint2*)(wp + di) = (uint2){pk_bf16x2(v.x, v.y), pk_bf16x2(v.z, v.w)};
}

// ---------------------------------------------------------------------------
// v8 GEMM body (proven) as device fn. 64x64 tile, BK=128, 4 waves, double-
// buffered LDS, drain-proof schedule, XCD-bijective swizzle, pre-shuffled W.
// Requirements: (M/64)%8==0, N%64==0, K%128==0.
struct GJob {
    const float* A; const float* A2;
    const unsigned short* Wp; const float* bias;
    float* Cf; unsigned short* Ch;
    int M, N, K, relu;
};

__device__ __forceinline__ void gemm_body(unsigned short* AsBase,   // 2 x 64*136
                                          const float* __restrict__ A,
                                          const float* __restrict__ A2,
                                          const unsigned short* __restrict__ Wp,
                                          const float* __restrict__ bias,
                                          float* __restrict__ Cf,
                                          unsigned short* __restrict__ Ch,
                                          int N, int K, int relu, unsigned bid) {
    const unsigned nc = (unsigned)N >> 6;
    const unsigned xcd = bid & 7, j = bid >> 3;
    const unsigned cpan = j % nc, r8 = j / nc;
    const int bm = (int)((xcd + (r8 << 3)) << 6);
    const int bn = (int)(cpan << 6);
    const int tid = threadIdx.x;
    const int wid = tid >> 6, lane = tid & 63;
    const int wr = wid >> 1, wc = wid & 1;       // wave tile: rows wr*32, cols wc*32
    const int col16 = lane & 15;
    const int quad = lane >> 4;

    const int srow0 = tid >> 4;            // 0..15
    const int scol = (tid & 15) * 4;       // 0..60
    const float* asrc = A + (size_t)(bm + srow0) * K + scol;
    const float* a2src = A2 ? A2 + (size_t)(bm + srow0) * K + scol : nullptr;

    const int K32 = K >> 5;
    const unsigned short* wbase = Wp + ((size_t)((bn >> 4) + wc * 2) * K32) * 512
                                + (size_t)lane * 8;

    floatx4 acc[2][2] = {};
    float4 rv[4][2];

    auto loadA = [&](int c) {
#pragma unroll
        for (int j2 = 0; j2 < 4; ++j2)
#pragma unroll
            for (int i = 0; i < 2; ++i)
                rv[j2][i] = *(const float4*)(asrc + (size_t)(16 * j2) * K + c * 128 + 64 * i);
        if (a2src) {
#pragma unroll
            for (int j2 = 0; j2 < 4; ++j2)
#pragma unroll
                for (int i = 0; i < 2; ++i) {
                    float4 t = *(const float4*)(a2src + (size_t)(16 * j2) * K + c * 128 + 64 * i);
                    rv[j2][i].x += t.x; rv[j2][i].y += t.y;
                    rv[j2][i].z += t.z; rv[j2][i].w += t.w;
                }
        }
    };
    auto writeA = [&](int buf) {
        unsigned short* dst = AsBase + buf * (64 * 136);
#pragma unroll
        for (int j2 = 0; j2 < 4; ++j2)
#pragma unroll
            for (int i = 0; i < 2; ++i) {
                uint2 p = {pk_bf16x2(rv[j2][i].x, rv[j2][i].y),
                           pk_bf16x2(rv[j2][i].z, rv[j2][i].w)};
                *(uint2*)&dst[(srow0 + 16 * j2) * 136 + scol + 64 * i] = p;
            }
    };

    const int NC = K >> 7;                 // chunks of 128
    loadA(0);
    writeA(0);

    for (int c = 0; c < NC; ++c) {
        __syncthreads();                    // buf[c&1] visible block-wide
        if (c + 1 < NC) loadA(c + 1);       // flies over the whole compute phase

        const unsigned short* ab = AsBase + (c & 1) * (64 * 136);
#pragma unroll
        for (int s = 0; s < 4; ++s) {
            bhalf8 bfr[2];
#pragma unroll
            for (int nt = 0; nt < 2; ++nt)
                bfr[nt] = *(const bhalf8*)(wbase + ((size_t)(nt * K32 + c * 4 + s)) * 512);
            bhalf8 af[2];
#pragma unroll
            for (int mt = 0; mt < 2; ++mt)
                af[mt] = *(const bhalf8*)&ab[(wr * 32 + mt * 16 + col16) * 136 + s * 32 + quad * 8];
#pragma unroll
            for (int mt = 0; mt < 2; ++mt)
#pragma unroll
                for (int nt = 0; nt < 2; ++nt)
                    acc[mt][nt] = __builtin_amdgcn_mfma_f32_16x16x32_bf16(
                        af[mt], bfr[nt], acc[mt][nt], 0, 0, 0);
        }

        if (c + 1 < NC) writeA((c + 1) & 1);  // per-wave vmcnt wait only, no barrier
    }

#pragma unroll
    for (int mt = 0; mt < 2; ++mt) {
#pragma unroll
        for (int nt = 0; nt < 2; ++nt) {
            const int col = bn + wc * 32 + nt * 16 + col16;
            const float bv = bias[col];
#pragma unroll
            for (int i = 0; i < 4; ++i) {
                const int row = bm + wr * 32 + mt * 16 + quad * 4 + i;
                float v = acc[mt][nt][i] + bv;
                if (relu) v = fmaxf(v, 0.f);
                if (Ch) Ch[(size_t)row * N + col] = bf16_1(v);
                else    Cf[(size_t)row * N + col] = v;
            }
        }
    }
}

__global__ __launch_bounds__(256, 4) void gemm_single(const float* __restrict__ A,
                                                      const float* __restrict__ A2,
                                                      const unsigned short* __restrict__ Wp,
                                                      const float* __restrict__ bias,
                                                      float* __restrict__ Cf,
                                                      unsigned short* __restrict__ Ch,
                                                      int N, int K, int relu) {
    __shared__ __attribute__((aligned(16))) unsigned short As[2 * 64 * 136]; // 34816 B
    gemm_body(As, A, A2, Wp, bias, Cf, Ch, N, K, relu, blockIdx.x);
}

// Three independent GEMMs in ONE dispatch: blocks [0,c0) run j0, [c0,c01) j1,
// [c01,grid) j2. Fills latency gaps of small GEMMs with big-GEMM blocks.
__global__ __launch_bounds__(256, 4) void gemm_triple(GJob j0, GJob j1, GJob j2,
                                                      unsigned c0, unsigned c01) {
    __shared__ __attribute__((aligned(16))) unsigned short As[2 * 64 * 136]; // 34816 B
    const unsigned b = blockIdx.x;
    if (b < c0) {
        gemm_body(As, j0.A, j0.A2, j0.Wp, j0.bias, j0.Cf, j0.Ch, j0.N, j0.K, j0.relu, b);
    } else if (b < c01) {
        gemm_body(As, j1.A, j1.A2, j1.Wp, j1.bias, j1.Cf, j1.Ch, j1.N, j1.K, j1.relu, b - c0);
    } else {
        gemm_body(As, j2.A, j2.A2, j2.Wp, j2.bias, j2.Cf, j2.Ch, j2.N, j2.K, j2.relu, b - c01);
    }
}

// ---------------------------------------------------------------------------
// v11: GEMM + residual + LayerNorm FUSED. N=256 fixed; block = 32 rows x 256
// cols (4 waves = 4 col panels of 64). out = LN(res + A@W^T + bias)*g + beta.
__global__ __launch_bounds__(256, 2) void gemm_ln(const float* __restrict__ A,
                                                  const unsigned short* __restrict__ Wp,
                                                  const float* __restrict__ bias,
                                                  const float* __restrict__ res,
                                                  const float* __restrict__ g,
                                                  const float* __restrict__ beta,
                                                  float* __restrict__ out,
                                                  int K) {
    __shared__ __attribute__((aligned(16))) unsigned short As[2][32 * 136]; // 17408 B
    const int bm = blockIdx.x * 32;
    const int tid = threadIdx.x;
    const int wid = tid >> 6, lane = tid & 63;
    const int col16 = lane & 15, quad = lane >> 4;
    const int wc = wid;                    // wave col panel: cols wc*64

    const int srow = tid >> 3;
    const int sc16 = (tid & 7) * 16;
    const float* asrc = A + (size_t)(bm + srow) * K + sc16;

    const int K32 = K >> 5;
    const unsigned short* wbase = Wp + (size_t)(wc * 4) * K32 * 512 + (size_t)lane * 8;

    floatx4 acc[2][4] = {};                // [mt][nt]
    float4 rv[4];

    auto loadA = [&](int c) {
#pragma unroll
        for (int j = 0; j < 4; ++j)
            rv[j] = *(const float4*)(asrc + c * 128 + j * 4);
    };
    auto writeA = [&](int buf) {
#pragma unroll
        for (int j = 0; j < 4; ++j) {
            uint2 p = {pk_bf16x2(rv[j].x, rv[j].y), pk_bf16x2(rv[j].z, rv[j].w)};
            *(uint2*)&As[buf][srow * 136 + sc16 + j * 4] = p;
        }
    };

    const int NC = K >> 7;
    loadA(0);
    writeA(0);

    for (int c = 0; c < NC; ++c) {
        __syncthreads();
        if (c + 1 < NC) loadA(c + 1);

        const unsigned short* ab = As[c & 1];
#pragma unroll
        for (int s = 0; s < 4; ++s) {
            bhalf8 bfr[4];
#pragma unroll
            for (int nt = 0; nt < 4; ++nt)
                bfr[nt] = *(const bhalf8*)(wbase + ((size_t)(nt * K32 + c * 4 + s)) * 512);
            bhalf8 af[2];
#pragma unroll
            for (int mt = 0; mt < 2; ++mt)
                af[mt] = *(const bhalf8*)&ab[(mt * 16 + col16) * 136 + s * 32 + quad * 8];
#pragma unroll
            for (int mt = 0; mt < 2; ++mt)
#pragma unroll
                for (int nt = 0; nt < 4; ++nt)
                    acc[mt][nt] = __builtin_amdgcn_mfma_f32_16x16x32_bf16(
                        af[mt], bfr[nt], acc[mt][nt], 0, 0, 0);
        }

        if (c + 1 < NC) writeA((c + 1) & 1);
    }

    // ---- fused epilogue: bias + residual, stats, LN, write
    float bias_r[4];
#pragma unroll
    for (int nt = 0; nt < 4; ++nt) bias_r[nt] = bias[wc * 64 + nt * 16 + col16];

    float s_[2][4], q_[2][4];
#pragma unroll
    for (int mt = 0; mt < 2; ++mt)
#pragma unroll
        for (int i = 0; i < 4; ++i) { s_[mt][i] = 0.f; q_[mt][i] = 0.f; }

#pragma unroll
    for (int mt = 0; mt < 2; ++mt)
#pragma unroll
        for (int i = 0; i < 4; ++i) {
            const int row = bm + mt * 16 + quad * 4 + i;
#pragma unroll
            for (int nt = 0; nt < 4; ++nt) {
                float r = res[(size_t)row * 256 + wc * 64 + nt * 16 + col16];
                float v = acc[mt][nt][i] + bias_r[nt] + r;
                acc[mt][nt][i] = v;
                s_[mt][i] += v;
                q_[mt][i] = fmaf(v, v, q_[mt][i]);
            }
        }

#pragma unroll
    for (int mt = 0; mt < 2; ++mt)
#pragma unroll
        for (int i = 0; i < 4; ++i) {
#pragma unroll
            for (int off = 1; off < 16; off <<= 1) {
                s_[mt][i] += __shfl_xor(s_[mt][i], off, 64);
                q_[mt][i] += __shfl_xor(q_[mt][i], off, 64);
            }
        }

    __syncthreads();                       // all As reads done; reuse as scratch
    float* red = (float*)As;
    if (col16 == 0) {
#pragma unroll
        for (int mt = 0; mt < 2; ++mt)
#pragma unroll
            for (int i = 0; i < 4; ++i) {
                red[wid * 32 + mt * 16 + quad * 4 + i] = s_[mt][i];
                red[128 + wid * 32 + mt * 16 + quad * 4 + i] = q_[mt][i];
            }
    }
    __syncthreads();
    float* mean_s = red + 256;
    float* rstd_s = red + 288;
    if (tid < 32) {
        float S = red[tid] + red[32 + tid] + red[64 + tid] + red[96 + tid];
        float Q = red[128 + tid] + red[160 + tid] + red[192 + tid] + red[224 + tid];
        float mean = S * (1.f / 256.f);
        float var = Q * (1.f / 256.f) - mean * mean;
        mean_s[tid] = mean;
        rstd_s[tid] = rsqrtf(var + 1e-5f);
    }
    __syncthreads();

    float g_r[4], b_r[4];
#pragma unroll
    for (int nt = 0; nt < 4; ++nt) {
        g_r[nt] = g[wc * 64 + nt * 16 + col16];
        b_r[nt] = beta[wc * 64 + nt * 16 + col16];
    }
#pragma unroll
    for (int mt = 0; mt < 2; ++mt)
#pragma unroll
        for (int i = 0; i < 4; ++i) {
            const int rl = mt * 16 + quad * 4 + i;
            const float mn = mean_s[rl], rs = rstd_s[rl];
#pragma unroll
            for (int nt = 0; nt < 4; ++nt)
                out[(size_t)(bm + rl) * 256 + wc * 64 + nt * 16 + col16] =
                    (acc[mt][nt][i] - mn) * rs * g_r[nt] + b_r[nt];
        }
}

// ---------------------------------------------------------------------------
// MFMA flash self-attention. grid (LQ/64, H, B), block 256 = 4 waves.
// v12: COALESCED K/V staging. Old staging was a 64-line-per-instruction
// gather (lane = row at 1KB stride) — ~2560 TA-cycles/tile/wave of pure
// address issue. New: thread (i,lane) covers row i*8+(lane>>3), cols
// (lane&7)*4 -> 8 lines of 128B per instruction (8x fewer); V transposes
// into the same Vt[d][k] layout via 4 cheap LDS scalar writes per load.
#define ATT_SCALE 0.17677669529663687f
__global__ __launch_bounds__(256, 2) void attn_mfma(const float* __restrict__ Q,
                                                    const float* __restrict__ Kb,
                                                    const float* __restrict__ Vb,
                                                    float* __restrict__ O,
                                                    int qk_stride) {
    const int b = blockIdx.z, h = blockIdx.y, qt = blockIdx.x;
    const int tid = threadIdx.x;
    const int wid = tid >> 6, lane = tid & 63;
    const int col16 = lane & 15, quad = lane >> 4;

    __shared__ unsigned short smem_us[40960];
    unsigned short* Ks = smem_us + wid * 9600;
    unsigned short* Vt = Ks + 2560;
    unsigned short* Ps = Ks + 4864;
    float* corr_s = (float*)(Ks + 9472);
    unsigned short* Qs = smem_us + 38400;

    // ---- stage Q (scaled) once, whole block
    {
        const int row = tid >> 2, part = tid & 3;
        const float* qsrc = Q + ((size_t)(b * LQv + qt * 64 + row)) * qk_stride + h * DHv + part * 8;
        float4 qa = *(const float4*)qsrc;
        float4 qb2 = *(const float4*)(qsrc + 4);
        uint4 qp = {pk_bf16x2(qa.x * ATT_SCALE, qa.y * ATT_SCALE),
                    pk_bf16x2(qa.z * ATT_SCALE, qa.w * ATT_SCALE),
                    pk_bf16x2(qb2.x * ATT_SCALE, qb2.y * ATT_SCALE),
                    pk_bf16x2(qb2.z * ATT_SCALE, qb2.w * ATT_SCALE)};
        *(uint4*)&Qs[row * 40 + part * 8] = qp;
    }
    __syncthreads();
    bhalf8 qfr[4];
#pragma unroll
    for (int j = 0; j < 4; ++j)
        qfr[j] = *(const bhalf8*)&Qs[(j * 16 + col16) * 40 + quad * 8];

    float m_state[4] = {-1e30f, -1e30f, -1e30f, -1e30f};
    float l_state[4] = {0.f, 0.f, 0.f, 0.f};
    floatx4 acc_o[4][2] = {};

    const float* kbase = Kb + ((size_t)(b * LQv + wid * 256)) * qk_stride + h * DHv;
    const float* vbase = Vb + ((size_t)(b * LQv + wid * 256)) * Cv + h * DHv;
    const int rsub = lane >> 3;            // 0..7
    const int c4 = (lane & 7) * 4;         // 0..28

#pragma unroll 1
    for (int t = 0; t < 4; ++t) {
        // ---- K stage: coalesced (8 rows x 128B per instruction)
        {
#pragma unroll
            for (int i = 0; i < 8; ++i) {
                const int row = i * 8 + rsub;
                const float4 f = *(const float4*)(kbase + (size_t)(t * 64 + row) * qk_stride + c4);
                *(uint2*)&Ks[row * 40 + c4] = (uint2){pk_bf16x2(f.x, f.y), pk_bf16x2(f.z, f.w)};
            }
        }
        // ---- V stage: coalesced read of V[k][d], transpose into Vt[d][k]
        //      via 4 scalar LDS writes per float4 (LDS scatter << global gather)
        {
#pragma unroll
            for (int i = 0; i < 8; ++i) {
                const int krow = i * 8 + rsub;
                const float4 f = *(const float4*)(vbase + (size_t)(t * 64 + krow) * Cv + c4);
                Vt[(c4 + 0) * 72 + krow] = bf16_1(f.x);
                Vt[(c4 + 1) * 72 + krow] = bf16_1(f.y);
                Vt[(c4 + 2) * 72 + krow] = bf16_1(f.z);
                Vt[(c4 + 3) * 72 + krow] = bf16_1(f.w);
            }
        }

        floatx4 accs[4][4] = {};
        bhalf8 af[4];
#pragma unroll
        for (int kf = 0; kf < 4; ++kf)
            af[kf] = *(const bhalf8*)&Ks[(kf * 16 + col16) * 40 + quad * 8];
#pragma unroll
        for (int kf = 0; kf < 4; ++kf)
#pragma unroll
            for (int qf = 0; qf < 4; ++qf)
                accs[kf][qf] = __builtin_amdgcn_mfma_f32_16x16x32_bf16(
                    af[kf], qfr[qf], accs[kf][qf], 0, 0, 0);

#pragma unroll
        for (int qf = 0; qf < 4; ++qf) {
            float tmax = -1e30f;
#pragma unroll
            for (int kf = 0; kf < 4; ++kf) {
                tmax = fmaxf(tmax, fmaxf(fmaxf(accs[kf][qf][0], accs[kf][qf][1]),
                                         fmaxf(accs[kf][qf][2], accs[kf][qf][3])));
            }
            tmax = fmaxf(tmax, __shfl_xor(tmax, 16));
            tmax = fmaxf(tmax, __shfl_xor(tmax, 32));
            float mnew = fmaxf(m_state[qf], tmax);
            float cr = __expf(m_state[qf] - mnew);
            m_state[qf] = mnew;
            float psum = 0.f;
#pragma unroll
            for (int kf = 0; kf < 4; ++kf) {
                float p0 = __expf(accs[kf][qf][0] - mnew);
                float p1 = __expf(accs[kf][qf][1] - mnew);
                float p2 = __expf(accs[kf][qf][2] - mnew);
                float p3 = __expf(accs[kf][qf][3] - mnew);
                psum += (p0 + p1) + (p2 + p3);
                uint2 pp = {pk_bf16x2(p0, p1), pk_bf16x2(p2, p3)};
                *(uint2*)&Ps[(qf * 16 + col16) * 72 + kf * 16 + quad * 4] = pp;
            }
            psum += __shfl_xor(psum, 16);
            psum += __shfl_xor(psum, 32);
            l_state[qf] = l_state[qf] * cr + psum;
            if (quad == 0) corr_s[qf * 16 + col16] = cr;
        }

#pragma unroll
        for (int mf = 0; mf < 4; ++mf) {
            float4 cv = *(const float4*)&corr_s[mf * 16 + quad * 4];
#pragma unroll
            for (int nf = 0; nf < 2; ++nf) {
                acc_o[mf][nf][0] *= cv.x;
                acc_o[mf][nf][1] *= cv.y;
                acc_o[mf][nf][2] *= cv.z;
                acc_o[mf][nf][3] *= cv.w;
            }
        }
#pragma unroll
        for (int ks2 = 0; ks2 < 2; ++ks2) {
            bhalf8 pf[4], vf[2];
#pragma unroll
            for (int mf = 0; mf < 4; ++mf)
                pf[mf] = *(const bhalf8*)&Ps[(mf * 16 + col16) * 72 + ks2 * 32 + quad * 8];
#pragma unroll
            for (int nf = 0; nf < 2; ++nf)
                vf[nf] = *(const bhalf8*)&Vt[(nf * 16 + col16) * 72 + ks2 * 32 + quad * 8];
#pragma unroll
            for (int mf = 0; mf < 4; ++mf)
#pragma unroll
                for (int nf = 0; nf < 2; ++nf)
                    acc_o[mf][nf] = __builtin_amdgcn_mfma_f32_16x16x32_bf16(
                        pf[mf], vf[nf], acc_o[mf][nf], 0, 0, 0);
        }
    }

    __syncthreads();
    float* mbuf = (float*)smem_us;
    float* lbuf = mbuf + 256;
    float* obuf = lbuf + 256;
    if (quad == 0) {
#pragma unroll
        for (int qf = 0; qf < 4; ++qf) {
            mbuf[wid * 64 + qf * 16 + col16] = m_state[qf];
            lbuf[wid * 64 + qf * 16 + col16] = l_state[qf];
        }
    }
#pragma unroll
    for (int mf = 0; mf < 4; ++mf)
#pragma unroll
        for (int nf = 0; nf < 2; ++nf)
#pragma unroll
            for (int i = 0; i < 4; ++i)
                obuf[wid * 2048 + (mf * 16 + quad * 4 + i) * 32 + nf * 16 + col16] =
                    acc_o[mf][nf][i];
    __syncthreads();
    {
        const int q = tid >> 2, dg = (tid & 3) * 8;
        float m0 = mbuf[q], m1 = mbuf[64 + q], m2 = mbuf[128 + q], m3 = mbuf[192 + q];
        float gm = fmaxf(fmaxf(m0, m1), fmaxf(m2, m3));
        float e0 = __expf(m0 - gm), e1 = __expf(m1 - gm);
        float e2 = __expf(m2 - gm), e3 = __expf(m3 - gm);
        float lt = lbuf[q] * e0 + lbuf[64 + q] * e1 + lbuf[128 + q] * e2 + lbuf[192 + q] * e3;
        float inv = 1.f / lt;
        const float* o0 = obuf + q * 32 + dg;
        float* orow = O + ((size_t)(b * LQv + qt * 64 + q)) * Cv + h * DHv + dg;
        float ov[8];
#pragma unroll
        for (int d = 0; d < 8; ++d)
            ov[d] = (o0[d] * e0 + o0[2048 + d] * e1 + o0[4096 + d] * e2 + o0[6144 + d] * e3) * inv;
        *(float4*)(orow) = make_float4(ov[0], ov[1], ov[2], ov[3]);
        *(float4*)(orow + 4) = make_float4(ov[4], ov[5], ov[6], ov[7]);
    }
}

// ---------------------------------------------------------------------------
// Deformable sampling over bf16 value. grid: B*LQ blocks, 256 thr = (h, d).
// offs+aw come MERGED in one [B*LQ][384] buffer: cols 0-255 offsets, 256-383 aw.
__global__ __launch_bounds__(256) void deform_sample(const unsigned short* __restrict__ value,
                                                     const float* __restrict__ oab,
                                                     const float* __restrict__ ref,
                                                     float* __restrict__ out) {
    const int bq = blockIdx.x;          // b*LQ + q
    const int b = bq >> 10;
    const int tid = threadIdx.x;
    const int h = tid >> 5, d = tid & 31;

    const float* aw = oab + (size_t)bq * 384 + 256 + h * 16;
    float w[16];
    float mx = -1e30f;
#pragma unroll
    for (int j = 0; j < 16; ++j) { w[j] = aw[j]; mx = fmaxf(mx, w[j]); }
    float ssum = 0.f;
#pragma unroll
    for (int j = 0; j < 16; ++j) { w[j] = __expf(w[j] - mx); ssum += w[j]; }
    float invs = 1.f / ssum;

    const float* op = oab + (size_t)bq * 384 + h * 32;
    const float* rp = ref + (size_t)bq * (Lv * 2);

    const int starts[4] = {0, 16384, 20480, 21504};
    const int WHl[4] = {128, 64, 32, 16};

    float acc = 0.f;
#pragma unroll 1
    for (int l = 0; l < 4; ++l) {
        const int wl = WHl[l];
        const float rx = rp[l * 2 + 0], ry = rp[l * 2 + 1];
        const unsigned short* vb0 = value + ((size_t)b * LSRCv + starts[l]) * Cv + h * DHv + d;
#pragma unroll 1
        for (int p = 0; p < 4; ++p) {
            float ox = op[l * 8 + p * 2 + 0], oy = op[l * 8 + p * 2 + 1];
            float x = rx * (float)wl + ox - 0.5f;
            float y = ry * (float)wl + oy - 0.5f;
            float fx0 = floorf(x), fy0 = floorf(y);
            int x0 = (int)fx0, y0 = (int)fy0;
            float tx = x - fx0, ty = y - fy0;
            float w00 = (1.f - tx) * (1.f - ty);
            float w10 = tx * (1.f - ty);
            float w01 = (1.f - tx) * ty;
            float w11 = tx * ty;
            float s = 0.f;
            bool xin0 = (x0 >= 0) & (x0 < wl);
            bool xin1 = (x0 + 1 >= 0) & (x0 + 1 < wl);
            bool yin0 = (y0 >= 0) & (y0 < wl);
            bool yin1 = (y0 + 1 >= 0) & (y0 + 1 < wl);
            if (yin0) {
                if (xin0) s = fmaf(w00, ubf2f(vb0[(size_t)(y0 * wl + x0) * Cv]), s);
                if (xin1) s = fmaf(w10, ubf2f(vb0[(size_t)(y0 * wl + x0 + 1) * Cv]), s);
            }
            if (yin1) {
                if (xin0) s = fmaf(w01, ubf2f(vb0[(size_t)((y0 + 1) * wl + x0) * Cv]), s);
                if (xin1) s = fmaf(w11, ubf2f(vb0[(size_t)((y0 + 1) * wl + x0 + 1) * Cv]), s);
            }
            acc = fmaf(w[l * 4 + p] * invs, s, acc);
        }
    }
    out[(size_t)bq * Cv + h * DHv + d] = acc;
}

// ---------------------------------------------------------------------------
extern "C" void kernel_launch(void* const* d_in, const int* in_sizes, int n_in,
                              void* d_out, int out_size, void* d_ws, size_t ws_size,
                              hipStream_t stream) {
    const float* tgt       = (const float*)d_in[0];
    const float* query_pos = (const float*)d_in[1];
    const float* ref_pts   = (const float*)d_in[2];
    const float* src       = (const float*)d_in[3];
    const float* in_w      = (const float*)d_in[4];
    const float* in_b      = (const float*)d_in[5];
    const float* sa_w      = (const float*)d_in[6];
    const float* sa_b      = (const float*)d_in[7];
    const float* off_w     = (const float*)d_in[8];
    const float* off_b     = (const float*)d_in[9];
    const float* aw_w      = (const float*)d_in[10];
    const float* aw_b      = (const float*)d_in[11];
    const float* val_w     = (const float*)d_in[12];
    const float* val_b     = (const float*)d_in[13];
    const float* co_w      = (const float*)d_in[14];
    const float* co_b      = (const float*)d_in[15];
    const float* ln1_g     = (const float*)d_in[16];
    const float* ln1_b     = (const float*)d_in[17];
    const float* ln2_g     = (const float*)d_in[18];
    const float* ln2_b     = (const float*)d_in[19];
    const float* ln3_g     = (const float*)d_in[20];
    const float* ln3_b     = (const float*)d_in[21];
    const float* f1_w      = (const float*)d_in[22];
    const float* f1_b      = (const float*)d_in[23];
    const float* f2_w      = (const float*)d_in[24];
    const float* f2_b      = (const float*)d_in[25];

    const int M0  = Bv * LQv * Cv;          // 1048576
    const int VSZ = Bv * LSRCv * Cv;        // 22282240
    float* ws = (float*)d_ws;

    // Layout:
    //   big[0..2M)      qkbuf [4096][512]
    //   big[2M..3M)     vb
    //   big[3M..4M)     ob
    //   big[4M..15.2M)  value16 (VSZ ushorts) — disjoint from qkbuf so the
    //                   value GEMM runs concurrently with qk/v (v10).
    //   big[20M..20.5M) wb (bf16 weights), cbias after.
    float* big    = ws;
    float* qkbuf  = big;
    float* vb     = big + (size_t)2 * M0;
    float* ob     = big + (size_t)3 * M0;
    unsigned short* value16 = (unsigned short*)(big + (size_t)4 * M0);
    unsigned short* wb = (unsigned short*)(big + (size_t)20000000);
    float* cbias  = big + (size_t)20510000;           // 384 f32
    float* tgt_a  = ws + (size_t)VSZ;
    float* oabuf  = tgt_a + M0;             // [4096][384] merged offsets+aw
    float* sampled= oabuf + (size_t)Bv * LQv * 384;
    float* tgt_b  = sampled + M0;
    float* hidden = tgt_b + M0;             // B*LQ*DFF

    // Fragment-shuffled bf16 weight segment offsets (ushort units)
    const size_t WB_IN = 0, WB_SA = 196608, WB_VAL = 262144, WB_OA = 327680,
                 WB_CO = 425984, WB_F1 = 491520, WB_F2 = 753664;

    const int Mq = Bv * LQv;                // 4096 rows
    dim3 blk256(256);

    // 0. pre-convert all weights to fragment-shuffled bf16 (one-time, ~2MB)
    cvt_weights<<<dim3(993), blk256, 0, stream>>>(
        in_w, sa_w, val_w, off_w, aw_w, co_w, f1_w, f2_w, off_b, aw_b, wb, cbias);

    // 1. FUSED dispatch: {qk proj, v proj, value proj} — mutually independent.
    {
        GJob jqk = {tgt, query_pos, wb + WB_IN, in_b, qkbuf, nullptr,
                    Mq, 512, Cv, 0};
        GJob jv  = {tgt, nullptr, wb + WB_IN + 131072, in_b + 2 * Cv, vb, nullptr,
                    Mq, Cv, Cv, 0};
        GJob jval= {src, nullptr, wb + WB_VAL, val_b, nullptr, value16,
                    Bv * LSRCv, Cv, Cv, 0};
        const unsigned c0 = (Mq / 64) * (512 / 64);          // 512
        const unsigned c1 = (Mq / 64) * (Cv / 64);           // 256
        const unsigned c2 = ((Bv * LSRCv) / 64) * (Cv / 64); // 5440
        gemm_triple<<<dim3(c0 + c1 + c2), blk256, 0, stream>>>(
            jqk, jv, jval, c0, c0 + c1);
    }

    // 2. self-attention (MFMA flash; Q/K strided in qkbuf)
    attn_mfma<<<dim3(LQv / 64, Hv, Bv), blk256, 0, stream>>>(qkbuf, qkbuf + 256, vb, ob, 512);

    // 3. FUSED sa-projection + LN2: tgt_a = LN(tgt + ob@sa_w^T + sa_b)
    gemm_ln<<<dim3(Mq / 32), blk256, 0, stream>>>(
        ob, wb + WB_SA, sa_b, tgt, ln2_g, ln2_b, tgt_a, Cv);

    // 4. MERGED offsets + aw logits GEMM (N=384, fused add A = tgt_a + query_pos)
    gemm_single<<<dim3((Mq / 64) * (384 / 64)), blk256, 0, stream>>>(
        tgt_a, query_pos, wb + WB_OA, cbias, oabuf, nullptr, 384, Cv, 0);

    // 5. deformable bilinear sampling (bf16 value)
    deform_sample<<<dim3(Bv * LQv), blk256, 0, stream>>>(value16, oabuf, ref_pts, sampled);

    // 6. FUSED cross-attn projection + LN1: tgt_b = LN(tgt_a + sampled@co_w^T + co_b)
    gemm_ln<<<dim3(Mq / 32), blk256, 0, stream>>>(
        sampled, wb + WB_CO, co_b, tgt_a, ln1_g, ln1_b, tgt_b, Cv);

    // 7. FFN up (relu)
    gemm_single<<<dim3((Mq / 64) * (DFFv / 64)), blk256, 0, stream>>>(
        tgt_b, nullptr, wb + WB_F1, f1_b, hidden, nullptr, DFFv, Cv, 1);

    // 8. FUSED FFN down + LN3 -> d_out
    gemm_ln<<<dim3(Mq / 32), blk256, 0, stream>>>(
        hidden, wb + WB_F2, f2_b, tgt_b, ln3_g, ln3_b, (float*)d_out, DFFv);
}

// Round 13
// 341.198 us; speedup vs baseline: 1.1238x; 1.0193x over previous
//
#include <hip/hip_runtime.h>
#include <hip/hip_bf16.h>
#include <math.h>

// Problem constants
#define Bv   4
#define LQv  1024
#define Cv   256
#define Hv   8
#define Lv   4
#define Pv   4
#define DFFv 1024
#define DHv  32
#define LSRCv 21760   // 128*128 + 64*64 + 32*32 + 16*16

typedef __attribute__((ext_vector_type(8))) short bhalf8;   // 8 bf16 (4 VGPRs)
typedef __attribute__((ext_vector_type(4))) float floatx4;  // MFMA acc

// fp32 -> bf16 RNE, packed pair
__device__ inline unsigned pk_bf16x2(float x, float y) {
    unsigned xb = __float_as_uint(x), yb = __float_as_uint(y);
    unsigned xr = (xb + 0x7FFFu + ((xb >> 16) & 1u)) >> 16;
    unsigned yr = (yb + 0x7FFFu + ((yb >> 16) & 1u)) >> 16;
    return xr | (yr << 16);
}
__device__ inline unsigned short bf16_1(float x) {
    unsigned xb = __float_as_uint(x);
    return (unsigned short)((xb + 0x7FFFu + ((xb >> 16) & 1u)) >> 16);
}
__device__ inline float ubf2f(unsigned short u) {
    return __uint_as_float(((unsigned)u) << 16);
}

// ---------------------------------------------------------------------------
// Weight pre-conversion: f32 [N][K] -> bf16 in FRAGMENT-SHUFFLED layout so that
// in-GEMM B-fragment loads are 64-lane contiguous 1KB streams:
//   ushort index = ((n>>4)*(K>>5) + (k>>5))*512 + ((k>>3)&3)*128 + (n&15)*8 + (k&7)
// Segments (f32 offsets): in_w 0, sa_w 196608, val_w 262144,
// MERGED off_w+aw_w 327680 (N=384: off rows n=0..255, aw rows n=256..383),
// co_w 425984, f1_w 491520, f2_w 753664; total 1015808 f32.
// Block gridDim-1 additionally builds the concatenated off/aw bias (384 f32).
__global__ __launch_bounds__(256) void cvt_weights(const float* __restrict__ in_w,
                                                   const float* __restrict__ sa_w,
                                                   const float* __restrict__ val_w,
                                                   const float* __restrict__ off_w,
                                                   const float* __restrict__ aw_w,
                                                   const float* __restrict__ co_w,
                                                   const float* __restrict__ f1_w,
                                                   const float* __restrict__ f2_w,
                                                   const float* __restrict__ off_b,
                                                   const float* __restrict__ aw_b,
                                                   unsigned short* __restrict__ wp,
                                                   float* __restrict__ cbias) {
    const size_t idx4 = (size_t)blockIdx.x * 256 + threadIdx.x;   // float4 index
    if (idx4 >= 253952) {                                          // 1015808/4
        const int t = (int)(idx4 - 253952);
        if (t < 256) cbias[t] = off_b[t];
        else if (t < 384) cbias[t] = aw_b[t - 256];
        return;
    }
    const size_t f = idx4 * 4;
    const float* src; size_t off; int K; size_t obase; int nadd = 0;
    if (f < 196608)      { src = in_w;  off = f;          K = 256;  obase = 0; }
    else if (f < 262144) { src = sa_w;  off = f - 196608; K = 256;  obase = 196608; }
    else if (f < 327680) { src = val_w; off = f - 262144; K = 256;  obase = 262144; }
    else if (f < 393216) { src = off_w; off = f - 327680; K = 256;  obase = 327680; }
    else if (f < 425984) { src = aw_w;  off = f - 393216; K = 256;  obase = 327680; nadd = 256; }
    else if (f < 491520) { src = co_w;  off = f - 425984; K = 256;  obase = 425984; }
    else if (f < 753664) { src = f1_w;  off = f - 491520; K = 256;  obase = 491520; }
    else                 { src = f2_w;  off = f - 753664; K = 1024; obase = 753664; }
    float4 v = *(const float4*)(src + off);
    const int n = (int)(off / (size_t)K) + nadd, k = (int)(off % (size_t)K);
    const size_t di = obase + ((size_t)((n >> 4) * (K >> 5) + (k >> 5))) * 512
                    + (size_t)(((k >> 3) & 3) * 128 + (n & 15) * 8 + (k & 7));
    *(uint2*)(wp + di) = (uint2){pk_bf16x2(v.x, v.y), pk_bf16x2(v.z, v.w)};
}

// ---------------------------------------------------------------------------
// v8 GEMM body (proven) as device fn. 64x64 tile, BK=128, 4 waves, double-
// buffered LDS, drain-proof schedule, XCD-bijective swizzle, pre-shuffled W.
// Requirements: (M/64)%8==0, N%64==0, K%128==0.
struct GJob {
    const float* A; const float* A2;
    const unsigned short* Wp; const float* bias;
    float* Cf; unsigned short* Ch;
    int M, N, K, relu;
};

__device__ __forceinline__ void gemm_body(unsigned short* AsBase,   // 2 x 64*136
                                          const float* __restrict__ A,
                                          const float* __restrict__ A2,
                                          const unsigned short* __restrict__ Wp,
                                          const float* __restrict__ bias,
                                          float* __restrict__ Cf,
                                          unsigned short* __restrict__ Ch,
                                          int N, int K, int relu, unsigned bid) {
    const unsigned nc = (unsigned)N >> 6;
    const unsigned xcd = bid & 7, j = bid >> 3;
    const unsigned cpan = j % nc, r8 = j / nc;
    const int bm = (int)((xcd + (r8 << 3)) << 6);
    const int bn = (int)(cpan << 6);
    const int tid = threadIdx.x;
    const int wid = tid >> 6, lane = tid & 63;
    const int wr = wid >> 1, wc = wid & 1;       // wave tile: rows wr*32, cols wc*32
    const int col16 = lane & 15;
    const int quad = lane >> 4;

    const int srow0 = tid >> 4;            // 0..15
    const int scol = (tid & 15) * 4;       // 0..60
    const float* asrc = A + (size_t)(bm + srow0) * K + scol;
    const float* a2src = A2 ? A2 + (size_t)(bm + srow0) * K + scol : nullptr;

    const int K32 = K >> 5;
    const unsigned short* wbase = Wp + ((size_t)((bn >> 4) + wc * 2) * K32) * 512
                                + (size_t)lane * 8;

    floatx4 acc[2][2] = {};
    float4 rv[4][2];

    auto loadA = [&](int c) {
#pragma unroll
        for (int j2 = 0; j2 < 4; ++j2)
#pragma unroll
            for (int i = 0; i < 2; ++i)
                rv[j2][i] = *(const float4*)(asrc + (size_t)(16 * j2) * K + c * 128 + 64 * i);
        if (a2src) {
#pragma unroll
            for (int j2 = 0; j2 < 4; ++j2)
#pragma unroll
                for (int i = 0; i < 2; ++i) {
                    float4 t = *(const float4*)(a2src + (size_t)(16 * j2) * K + c * 128 + 64 * i);
                    rv[j2][i].x += t.x; rv[j2][i].y += t.y;
                    rv[j2][i].z += t.z; rv[j2][i].w += t.w;
                }
        }
    };
    auto writeA = [&](int buf) {
        unsigned short* dst = AsBase + buf * (64 * 136);
#pragma unroll
        for (int j2 = 0; j2 < 4; ++j2)
#pragma unroll
            for (int i = 0; i < 2; ++i) {
                uint2 p = {pk_bf16x2(rv[j2][i].x, rv[j2][i].y),
                           pk_bf16x2(rv[j2][i].z, rv[j2][i].w)};
                *(uint2*)&dst[(srow0 + 16 * j2) * 136 + scol + 64 * i] = p;
            }
    };

    const int NC = K >> 7;                 // chunks of 128
    loadA(0);
    writeA(0);

    for (int c = 0; c < NC; ++c) {
        __syncthreads();                    // buf[c&1] visible block-wide
        if (c + 1 < NC) loadA(c + 1);       // flies over the whole compute phase

        const unsigned short* ab = AsBase + (c & 1) * (64 * 136);
#pragma unroll
        for (int s = 0; s < 4; ++s) {
            bhalf8 bfr[2];
#pragma unroll
            for (int nt = 0; nt < 2; ++nt)
                bfr[nt] = *(const bhalf8*)(wbase + ((size_t)(nt * K32 + c * 4 + s)) * 512);
            bhalf8 af[2];
#pragma unroll
            for (int mt = 0; mt < 2; ++mt)
                af[mt] = *(const bhalf8*)&ab[(wr * 32 + mt * 16 + col16) * 136 + s * 32 + quad * 8];
#pragma unroll
            for (int mt = 0; mt < 2; ++mt)
#pragma unroll
                for (int nt = 0; nt < 2; ++nt)
                    acc[mt][nt] = __builtin_amdgcn_mfma_f32_16x16x32_bf16(
                        af[mt], bfr[nt], acc[mt][nt], 0, 0, 0);
        }

        if (c + 1 < NC) writeA((c + 1) & 1);  // per-wave vmcnt wait only, no barrier
    }

#pragma unroll
    for (int mt = 0; mt < 2; ++mt) {
#pragma unroll
        for (int nt = 0; nt < 2; ++nt) {
            const int col = bn + wc * 32 + nt * 16 + col16;
            const float bv = bias[col];
#pragma unroll
            for (int i = 0; i < 4; ++i) {
                const int row = bm + wr * 32 + mt * 16 + quad * 4 + i;
                float v = acc[mt][nt][i] + bv;
                if (relu) v = fmaxf(v, 0.f);
                if (Ch) Ch[(size_t)row * N + col] = bf16_1(v);
                else    Cf[(size_t)row * N + col] = v;
            }
        }
    }
}

__global__ __launch_bounds__(256, 4) void gemm_single(const float* __restrict__ A,
                                                      const float* __restrict__ A2,
                                                      const unsigned short* __restrict__ Wp,
                                                      const float* __restrict__ bias,
                                                      float* __restrict__ Cf,
                                                      unsigned short* __restrict__ Ch,
                                                      int N, int K, int relu) {
    __shared__ __attribute__((aligned(16))) unsigned short As[2 * 64 * 136]; // 34816 B
    gemm_body(As, A, A2, Wp, bias, Cf, Ch, N, K, relu, blockIdx.x);
}

// Three independent GEMMs in ONE dispatch: blocks [0,c0) run j0, [c0,c01) j1,
// [c01,grid) j2. Fills latency gaps of small GEMMs with big-GEMM blocks.
__global__ __launch_bounds__(256, 4) void gemm_triple(GJob j0, GJob j1, GJob j2,
                                                      unsigned c0, unsigned c01) {
    __shared__ __attribute__((aligned(16))) unsigned short As[2 * 64 * 136]; // 34816 B
    const unsigned b = blockIdx.x;
    if (b < c0) {
        gemm_body(As, j0.A, j0.A2, j0.Wp, j0.bias, j0.Cf, j0.Ch, j0.N, j0.K, j0.relu, b);
    } else if (b < c01) {
        gemm_body(As, j1.A, j1.A2, j1.Wp, j1.bias, j1.Cf, j1.Ch, j1.N, j1.K, j1.relu, b - c0);
    } else {
        gemm_body(As, j2.A, j2.A2, j2.Wp, j2.bias, j2.Cf, j2.Ch, j2.N, j2.K, j2.relu, b - c01);
    }
}

// ---------------------------------------------------------------------------
// v13 gemm_ln: GEMM + residual + LayerNorm fused, bf16 A input, 16-ROW blocks.
// grid = M/16 = 256 blocks (v11's 32-row/128-block version left HALF the GPU
// idle). N=256 fixed; 4 waves = 4 col panels of 64, each wave 4 n-frags.
// A is bf16 (all producers now emit bf16 directly — identical RNE rounding to
// the old store-f32-then-convert path, so results are bit-identical).
// out = LN(res + Ah@W^T + bias)*g + beta.  K%128==0 (256 or 1024).
__global__ __launch_bounds__(256, 4) void gemm_ln(const unsigned short* __restrict__ Ah,
                                                  const unsigned short* __restrict__ Wp,
                                                  const float* __restrict__ bias,
                                                  const float* __restrict__ res,
                                                  const float* __restrict__ g,
                                                  const float* __restrict__ beta,
                                                  float* __restrict__ out,
                                                  int K) {
    __shared__ __attribute__((aligned(16))) unsigned short As[2][16 * 136]; // 8704 B
    const int bm = blockIdx.x * 16;
    const int tid = threadIdx.x;
    const int wid = tid >> 6, lane = tid & 63;
    const int col16 = lane & 15, quad = lane >> 4;
    const int wc = wid;                    // wave col panel: cols wc*64

    // staging: thread covers row tid>>4 (0..15), bf16 cols (tid&15)*8 .. +8
    const int srow = tid >> 4;
    const int sc8 = (tid & 15) * 8;
    const unsigned short* asrc = Ah + (size_t)(bm + srow) * K + sc8;

    const int K32 = K >> 5;
    const unsigned short* wbase = Wp + (size_t)(wc * 4) * K32 * 512 + (size_t)lane * 8;

    floatx4 acc[4] = {};                   // [nt]
    uint4 rvh;

    auto loadA = [&](int c) { rvh = *(const uint4*)(asrc + c * 128); };
    auto writeA = [&](int buf) { *(uint4*)&As[buf][srow * 136 + sc8] = rvh; };

    const int NC = K >> 7;
    loadA(0);
    writeA(0);

    for (int c = 0; c < NC; ++c) {
        __syncthreads();
        if (c + 1 < NC) loadA(c + 1);

        const unsigned short* ab = As[c & 1];
#pragma unroll
        for (int s = 0; s < 4; ++s) {
            bhalf8 bfr[4];
#pragma unroll
            for (int nt = 0; nt < 4; ++nt)
                bfr[nt] = *(const bhalf8*)(wbase + ((size_t)(nt * K32 + c * 4 + s)) * 512);
            bhalf8 af = *(const bhalf8*)&ab[col16 * 136 + s * 32 + quad * 8];
#pragma unroll
            for (int nt = 0; nt < 4; ++nt)
                acc[nt] = __builtin_amdgcn_mfma_f32_16x16x32_bf16(
                    af, bfr[nt], acc[nt], 0, 0, 0);
        }

        if (c + 1 < NC) writeA((c + 1) & 1);
    }

    // ---- fused epilogue: bias + residual, stats, LN, write
    float bias_r[4];
#pragma unroll
    for (int nt = 0; nt < 4; ++nt) bias_r[nt] = bias[wc * 64 + nt * 16 + col16];

    float s_[4] = {}, q_[4] = {};
#pragma unroll
    for (int i = 0; i < 4; ++i) {
        const int row = bm + quad * 4 + i;
#pragma unroll
        for (int nt = 0; nt < 4; ++nt) {
            float r = res[(size_t)row * 256 + wc * 64 + nt * 16 + col16];
            float v = acc[nt][i] + bias_r[nt] + r;
            acc[nt][i] = v;
            s_[i] += v;
            q_[i] = fmaf(v, v, q_[i]);
        }
    }

#pragma unroll
    for (int i = 0; i < 4; ++i) {
#pragma unroll
        for (int off = 1; off < 16; off <<= 1) {
            s_[i] += __shfl_xor(s_[i], off, 64);
            q_[i] += __shfl_xor(q_[i], off, 64);
        }
    }

    __syncthreads();                       // all As reads done; reuse as scratch
    float* red = (float*)As;               // sums [4][16], sqs +64, mean +128, rstd +144
    if (col16 == 0) {
#pragma unroll
        for (int i = 0; i < 4; ++i) {
            red[wid * 16 + quad * 4 + i] = s_[i];
            red[64 + wid * 16 + quad * 4 + i] = q_[i];
        }
    }
    __syncthreads();
    float* mean_s = red + 128;
    float* rstd_s = red + 144;
    if (tid < 16) {
        float S = red[tid] + red[16 + tid] + red[32 + tid] + red[48 + tid];
        float Q = red[64 + tid] + red[80 + tid] + red[96 + tid] + red[112 + tid];
        float mean = S * (1.f / 256.f);
        float var = Q * (1.f / 256.f) - mean * mean;
        mean_s[tid] = mean;
        rstd_s[tid] = rsqrtf(var + 1e-5f);
    }
    __syncthreads();

    float g_r[4], b_r[4];
#pragma unroll
    for (int nt = 0; nt < 4; ++nt) {
        g_r[nt] = g[wc * 64 + nt * 16 + col16];
        b_r[nt] = beta[wc * 64 + nt * 16 + col16];
    }
#pragma unroll
    for (int i = 0; i < 4; ++i) {
        const int rl = quad * 4 + i;
        const float mn = mean_s[rl], rs = rstd_s[rl];
#pragma unroll
        for (int nt = 0; nt < 4; ++nt)
            out[(size_t)(bm + rl) * 256 + wc * 64 + nt * 16 + col16] =
                (acc[nt][i] - mn) * rs * g_r[nt] + b_r[nt];
    }
}

// ---------------------------------------------------------------------------
// MFMA flash self-attention. grid (LQ/64, H, B), block 256 = 4 waves.
// v12 coalesced K/V staging; v13: output written as bf16 (consumer sa-proj
// quantized it anyway — identical RNE path, halves ob traffic).
#define ATT_SCALE 0.17677669529663687f
__global__ __launch_bounds__(256, 2) void attn_mfma(const float* __restrict__ Q,
                                                    const float* __restrict__ Kb,
                                                    const float* __restrict__ Vb,
                                                    unsigned short* __restrict__ O,
                                                    int qk_stride) {
    const int b = blockIdx.z, h = blockIdx.y, qt = blockIdx.x;
    const int tid = threadIdx.x;
    const int wid = tid >> 6, lane = tid & 63;
    const int col16 = lane & 15, quad = lane >> 4;

    __shared__ unsigned short smem_us[40960];
    unsigned short* Ks = smem_us + wid * 9600;
    unsigned short* Vt = Ks + 2560;
    unsigned short* Ps = Ks + 4864;
    float* corr_s = (float*)(Ks + 9472);
    unsigned short* Qs = smem_us + 38400;

    // ---- stage Q (scaled) once, whole block
    {
        const int row = tid >> 2, part = tid & 3;
        const float* qsrc = Q + ((size_t)(b * LQv + qt * 64 + row)) * qk_stride + h * DHv + part * 8;
        float4 qa = *(const float4*)qsrc;
        float4 qb2 = *(const float4*)(qsrc + 4);
        uint4 qp = {pk_bf16x2(qa.x * ATT_SCALE, qa.y * ATT_SCALE),
                    pk_bf16x2(qa.z * ATT_SCALE, qa.w * ATT_SCALE),
                    pk_bf16x2(qb2.x * ATT_SCALE, qb2.y * ATT_SCALE),
                    pk_bf16x2(qb2.z * ATT_SCALE, qb2.w * ATT_SCALE)};
        *(uint4*)&Qs[row * 40 + part * 8] = qp;
    }
    __syncthreads();
    bhalf8 qfr[4];
#pragma unroll
    for (int j = 0; j < 4; ++j)
        qfr[j] = *(const bhalf8*)&Qs[(j * 16 + col16) * 40 + quad * 8];

    float m_state[4] = {-1e30f, -1e30f, -1e30f, -1e30f};
    float l_state[4] = {0.f, 0.f, 0.f, 0.f};
    floatx4 acc_o[4][2] = {};

    const float* kbase = Kb + ((size_t)(b * LQv + wid * 256)) * qk_stride + h * DHv;
    const float* vbase = Vb + ((size_t)(b * LQv + wid * 256)) * Cv + h * DHv;
    const int rsub = lane >> 3;            // 0..7
    const int c4 = (lane & 7) * 4;         // 0..28

#pragma unroll 1
    for (int t = 0; t < 4; ++t) {
        // ---- K stage: coalesced (8 rows x 128B per instruction)
        {
#pragma unroll
            for (int i = 0; i < 8; ++i) {
                const int row = i * 8 + rsub;
                const float4 f = *(const float4*)(kbase + (size_t)(t * 64 + row) * qk_stride + c4);
                *(uint2*)&Ks[row * 40 + c4] = (uint2){pk_bf16x2(f.x, f.y), pk_bf16x2(f.z, f.w)};
            }
        }
        // ---- V stage: coalesced read of V[k][d], transpose into Vt[d][k]
        {
#pragma unroll
            for (int i = 0; i < 8; ++i) {
                const int krow = i * 8 + rsub;
                const float4 f = *(const float4*)(vbase + (size_t)(t * 64 + krow) * Cv + c4);
                Vt[(c4 + 0) * 72 + krow] = bf16_1(f.x);
                Vt[(c4 + 1) * 72 + krow] = bf16_1(f.y);
                Vt[(c4 + 2) * 72 + krow] = bf16_1(f.z);
                Vt[(c4 + 3) * 72 + krow] = bf16_1(f.w);
            }
        }

        floatx4 accs[4][4] = {};
        bhalf8 af[4];
#pragma unroll
        for (int kf = 0; kf < 4; ++kf)
            af[kf] = *(const bhalf8*)&Ks[(kf * 16 + col16) * 40 + quad * 8];
#pragma unroll
        for (int kf = 0; kf < 4; ++kf)
#pragma unroll
            for (int qf = 0; qf < 4; ++qf)
                accs[kf][qf] = __builtin_amdgcn_mfma_f32_16x16x32_bf16(
                    af[kf], qfr[qf], accs[kf][qf], 0, 0, 0);

#pragma unroll
        for (int qf = 0; qf < 4; ++qf) {
            float tmax = -1e30f;
#pragma unroll
            for (int kf = 0; kf < 4; ++kf) {
                tmax = fmaxf(tmax, fmaxf(fmaxf(accs[kf][qf][0], accs[kf][qf][1]),
                                         fmaxf(accs[kf][qf][2], accs[kf][qf][3])));
            }
            tmax = fmaxf(tmax, __shfl_xor(tmax, 16));
            tmax = fmaxf(tmax, __shfl_xor(tmax, 32));
            float mnew = fmaxf(m_state[qf], tmax);
            float cr = __expf(m_state[qf] - mnew);
            m_state[qf] = mnew;
            float psum = 0.f;
#pragma unroll
            for (int kf = 0; kf < 4; ++kf) {
                float p0 = __expf(accs[kf][qf][0] - mnew);
                float p1 = __expf(accs[kf][qf][1] - mnew);
                float p2 = __expf(accs[kf][qf][2] - mnew);
                float p3 = __expf(accs[kf][qf][3] - mnew);
                psum += (p0 + p1) + (p2 + p3);
                uint2 pp = {pk_bf16x2(p0, p1), pk_bf16x2(p2, p3)};
                *(uint2*)&Ps[(qf * 16 + col16) * 72 + kf * 16 + quad * 4] = pp;
            }
            psum += __shfl_xor(psum, 16);
            psum += __shfl_xor(psum, 32);
            l_state[qf] = l_state[qf] * cr + psum;
            if (quad == 0) corr_s[qf * 16 + col16] = cr;
        }

#pragma unroll
        for (int mf = 0; mf < 4; ++mf) {
            float4 cv = *(const float4*)&corr_s[mf * 16 + quad * 4];
#pragma unroll
            for (int nf = 0; nf < 2; ++nf) {
                acc_o[mf][nf][0] *= cv.x;
                acc_o[mf][nf][1] *= cv.y;
                acc_o[mf][nf][2] *= cv.z;
                acc_o[mf][nf][3] *= cv.w;
            }
        }
#pragma unroll
        for (int ks2 = 0; ks2 < 2; ++ks2) {
            bhalf8 pf[4], vf[2];
#pragma unroll
            for (int mf = 0; mf < 4; ++mf)
                pf[mf] = *(const bhalf8*)&Ps[(mf * 16 + col16) * 72 + ks2 * 32 + quad * 8];
#pragma unroll
            for (int nf = 0; nf < 2; ++nf)
                vf[nf] = *(const bhalf8*)&Vt[(nf * 16 + col16) * 72 + ks2 * 32 + quad * 8];
#pragma unroll
            for (int mf = 0; mf < 4; ++mf)
#pragma unroll
                for (int nf = 0; nf < 2; ++nf)
                    acc_o[mf][nf] = __builtin_amdgcn_mfma_f32_16x16x32_bf16(
                        pf[mf], vf[nf], acc_o[mf][nf], 0, 0, 0);
        }
    }

    __syncthreads();
    float* mbuf = (float*)smem_us;
    float* lbuf = mbuf + 256;
    float* obuf = lbuf + 256;
    if (quad == 0) {
#pragma unroll
        for (int qf = 0; qf < 4; ++qf) {
            mbuf[wid * 64 + qf * 16 + col16] = m_state[qf];
            lbuf[wid * 64 + qf * 16 + col16] = l_state[qf];
        }
    }
#pragma unroll
    for (int mf = 0; mf < 4; ++mf)
#pragma unroll
        for (int nf = 0; nf < 2; ++nf)
#pragma unroll
            for (int i = 0; i < 4; ++i)
                obuf[wid * 2048 + (mf * 16 + quad * 4 + i) * 32 + nf * 16 + col16] =
                    acc_o[mf][nf][i];
    __syncthreads();
    {
        const int q = tid >> 2, dg = (tid & 3) * 8;
        float m0 = mbuf[q], m1 = mbuf[64 + q], m2 = mbuf[128 + q], m3 = mbuf[192 + q];
        float gm = fmaxf(fmaxf(m0, m1), fmaxf(m2, m3));
        float e0 = __expf(m0 - gm), e1 = __expf(m1 - gm);
        float e2 = __expf(m2 - gm), e3 = __expf(m3 - gm);
        float lt = lbuf[q] * e0 + lbuf[64 + q] * e1 + lbuf[128 + q] * e2 + lbuf[192 + q] * e3;
        float inv = 1.f / lt;
        const float* o0 = obuf + q * 32 + dg;
        unsigned short* orow = O + ((size_t)(b * LQv + qt * 64 + q)) * Cv + h * DHv + dg;
        float ov[8];
#pragma unroll
        for (int d = 0; d < 8; ++d)
            ov[d] = (o0[d] * e0 + o0[2048 + d] * e1 + o0[4096 + d] * e2 + o0[6144 + d] * e3) * inv;
        uint4 op = {pk_bf16x2(ov[0], ov[1]), pk_bf16x2(ov[2], ov[3]),
                    pk_bf16x2(ov[4], ov[5]), pk_bf16x2(ov[6], ov[7])};
        *(uint4*)orow = op;
    }
}

// ---------------------------------------------------------------------------
// Deformable sampling over bf16 value. grid: B*LQ blocks, 256 thr = (h, d).
// offs+aw come MERGED in one [B*LQ][384] buffer: cols 0-255 offsets, 256-383 aw.
// v13: output written as bf16 (consumer co-proj quantized it anyway).
__global__ __launch_bounds__(256) void deform_sample(const unsigned short* __restrict__ value,
                                                     const float* __restrict__ oab,
                                                     const float* __restrict__ ref,
                                                     unsigned short* __restrict__ out) {
    const int bq = blockIdx.x;          // b*LQ + q
    const int b = bq >> 10;
    const int tid = threadIdx.x;
    const int h = tid >> 5, d = tid & 31;

    const float* aw = oab + (size_t)bq * 384 + 256 + h * 16;
    float w[16];
    float mx = -1e30f;
#pragma unroll
    for (int j = 0; j < 16; ++j) { w[j] = aw[j]; mx = fmaxf(mx, w[j]); }
    float ssum = 0.f;
#pragma unroll
    for (int j = 0; j < 16; ++j) { w[j] = __expf(w[j] - mx); ssum += w[j]; }
    float invs = 1.f / ssum;

    const float* op = oab + (size_t)bq * 384 + h * 32;
    const float* rp = ref + (size_t)bq * (Lv * 2);

    const int starts[4] = {0, 16384, 20480, 21504};
    const int WHl[4] = {128, 64, 32, 16};

    float acc = 0.f;
#pragma unroll 1
    for (int l = 0; l < 4; ++l) {
        const int wl = WHl[l];
        const float rx = rp[l * 2 + 0], ry = rp[l * 2 + 1];
        const unsigned short* vb0 = value + ((size_t)b * LSRCv + starts[l]) * Cv + h * DHv + d;
#pragma unroll 1
        for (int p = 0; p < 4; ++p) {
            float ox = op[l * 8 + p * 2 + 0], oy = op[l * 8 + p * 2 + 1];
            float x = rx * (float)wl + ox - 0.5f;
            float y = ry * (float)wl + oy - 0.5f;
            float fx0 = floorf(x), fy0 = floorf(y);
            int x0 = (int)fx0, y0 = (int)fy0;
            float tx = x - fx0, ty = y - fy0;
            float w00 = (1.f - tx) * (1.f - ty);
            float w10 = tx * (1.f - ty);
            float w01 = (1.f - tx) * ty;
            float w11 = tx * ty;
            float s = 0.f;
            bool xin0 = (x0 >= 0) & (x0 < wl);
            bool xin1 = (x0 + 1 >= 0) & (x0 + 1 < wl);
            bool yin0 = (y0 >= 0) & (y0 < wl);
            bool yin1 = (y0 + 1 >= 0) & (y0 + 1 < wl);
            if (yin0) {
                if (xin0) s = fmaf(w00, ubf2f(vb0[(size_t)(y0 * wl + x0) * Cv]), s);
                if (xin1) s = fmaf(w10, ubf2f(vb0[(size_t)(y0 * wl + x0 + 1) * Cv]), s);
            }
            if (yin1) {
                if (xin0) s = fmaf(w01, ubf2f(vb0[(size_t)((y0 + 1) * wl + x0) * Cv]), s);
                if (xin1) s = fmaf(w11, ubf2f(vb0[(size_t)((y0 + 1) * wl + x0 + 1) * Cv]), s);
            }
            acc = fmaf(w[l * 4 + p] * invs, s, acc);
        }
    }
    out[(size_t)bq * Cv + h * DHv + d] = bf16_1(acc);
}

// ---------------------------------------------------------------------------
extern "C" void kernel_launch(void* const* d_in, const int* in_sizes, int n_in,
                              void* d_out, int out_size, void* d_ws, size_t ws_size,
                              hipStream_t stream) {
    const float* tgt       = (const float*)d_in[0];
    const float* query_pos = (const float*)d_in[1];
    const float* ref_pts   = (const float*)d_in[2];
    const float* src       = (const float*)d_in[3];
    const float* in_w      = (const float*)d_in[4];
    const float* in_b      = (const float*)d_in[5];
    const float* sa_w      = (const float*)d_in[6];
    const float* sa_b      = (const float*)d_in[7];
    const float* off_w     = (const float*)d_in[8];
    const float* off_b     = (const float*)d_in[9];
    const float* aw_w      = (const float*)d_in[10];
    const float* aw_b      = (const float*)d_in[11];
    const float* val_w     = (const float*)d_in[12];
    const float* val_b     = (const float*)d_in[13];
    const float* co_w      = (const float*)d_in[14];
    const float* co_b      = (const float*)d_in[15];
    const float* ln1_g     = (const float*)d_in[16];
    const float* ln1_b     = (const float*)d_in[17];
    const float* ln2_g     = (const float*)d_in[18];
    const float* ln2_b     = (const float*)d_in[19];
    const float* ln3_g     = (const float*)d_in[20];
    const float* ln3_b     = (const float*)d_in[21];
    const float* f1_w      = (const float*)d_in[22];
    const float* f1_b      = (const float*)d_in[23];
    const float* f2_w      = (const float*)d_in[24];
    const float* f2_b      = (const float*)d_in[25];

    const int M0  = Bv * LQv * Cv;          // 1048576
    const int VSZ = Bv * LSRCv * Cv;        // 22282240
    float* ws = (float*)d_ws;

    // Layout:
    //   big[0..2M)      qkbuf [4096][512]
    //   big[2M..3M)     vb
    //   big[3M..3.5M)   ob16 (bf16, 2 MB)
    //   big[4M..15.2M)  value16 (VSZ ushorts) — disjoint from qkbuf so the
    //                   value GEMM runs concurrently with qk/v (v10).
    //   big[20M..20.5M) wb (bf16 weights), cbias after.
    float* big    = ws;
    float* qkbuf  = big;
    float* vb     = big + (size_t)2 * M0;
    unsigned short* ob16 = (unsigned short*)(big + (size_t)3 * M0);
    unsigned short* value16 = (unsigned short*)(big + (size_t)4 * M0);
    unsigned short* wb = (unsigned short*)(big + (size_t)20000000);
    float* cbias  = big + (size_t)20510000;           // 384 f32
    float* tgt_a  = ws + (size_t)VSZ;
    float* oabuf  = tgt_a + M0;             // [4096][384] merged offsets+aw
    unsigned short* sampled16 = (unsigned short*)(oabuf + (size_t)Bv * LQv * 384);
    float* tgt_b  = (float*)(sampled16 + M0);          // M0 ushorts then tgt_b
    unsigned short* hidden16 = (unsigned short*)(tgt_b + M0);   // B*LQ*DFF ushorts

    // Fragment-shuffled bf16 weight segment offsets (ushort units)
    const size_t WB_IN = 0, WB_SA = 196608, WB_VAL = 262144, WB_OA = 327680,
                 WB_CO = 425984, WB_F1 = 491520, WB_F2 = 753664;

    const int Mq = Bv * LQv;                // 4096 rows
    dim3 blk256(256);

    // 0. pre-convert all weights to fragment-shuffled bf16 (one-time, ~2MB)
    cvt_weights<<<dim3(993), blk256, 0, stream>>>(
        in_w, sa_w, val_w, off_w, aw_w, co_w, f1_w, f2_w, off_b, aw_b, wb, cbias);

    // 1. FUSED dispatch: {qk proj, v proj, value proj} — mutually independent.
    {
        GJob jqk = {tgt, query_pos, wb + WB_IN, in_b, qkbuf, nullptr,
                    Mq, 512, Cv, 0};
        GJob jv  = {tgt, nullptr, wb + WB_IN + 131072, in_b + 2 * Cv, vb, nullptr,
                    Mq, Cv, Cv, 0};
        GJob jval= {src, nullptr, wb + WB_VAL, val_b, nullptr, value16,
                    Bv * LSRCv, Cv, Cv, 0};
        const unsigned c0 = (Mq / 64) * (512 / 64);          // 512
        const unsigned c1 = (Mq / 64) * (Cv / 64);           // 256
        const unsigned c2 = ((Bv * LSRCv) / 64) * (Cv / 64); // 5440
        gemm_triple<<<dim3(c0 + c1 + c2), blk256, 0, stream>>>(
            jqk, jv, jval, c0, c0 + c1);
    }

    // 2. self-attention (MFMA flash; Q/K strided in qkbuf) -> bf16 ob
    attn_mfma<<<dim3(LQv / 64, Hv, Bv), blk256, 0, stream>>>(qkbuf, qkbuf + 256, vb, ob16, 512);

    // 3. FUSED sa-projection + LN2: tgt_a = LN(tgt + ob@sa_w^T + sa_b)
    gemm_ln<<<dim3(Mq / 16), blk256, 0, stream>>>(
        ob16, wb + WB_SA, sa_b, tgt, ln2_g, ln2_b, tgt_a, Cv);

    // 4. MERGED offsets + aw logits GEMM (N=384, fused add A = tgt_a + query_pos)
    gemm_single<<<dim3((Mq / 64) * (384 / 64)), blk256, 0, stream>>>(
        tgt_a, query_pos, wb + WB_OA, cbias, oabuf, nullptr, 384, Cv, 0);

    // 5. deformable bilinear sampling (bf16 value) -> bf16 sampled
    deform_sample<<<dim3(Bv * LQv), blk256, 0, stream>>>(value16, oabuf, ref_pts, sampled16);

    // 6. FUSED cross-attn projection + LN1: tgt_b = LN(tgt_a + sampled@co_w^T + co_b)
    gemm_ln<<<dim3(Mq / 16), blk256, 0, stream>>>(
        sampled16, wb + WB_CO, co_b, tgt_a, ln1_g, ln1_b, tgt_b, Cv);

    // 7. FFN up (relu) -> bf16 hidden
    gemm_single<<<dim3((Mq / 64) * (DFFv / 64)), blk256, 0, stream>>>(
        tgt_b, nullptr, wb + WB_F1, f1_b, nullptr, hidden16, DFFv, Cv, 1);

    // 8. FUSED FFN down + LN3 -> d_out
    gemm_ln<<<dim3(Mq / 16), blk256, 0, stream>>>(
        hidden16, wb + WB_F2, f2_b, tgt_b, ln3_g, ln3_b, (float*)d_out, DFFv);
}